// Round 1
// baseline (1483.177 us; speedup 1.0000x reference)
//
#include <hip/hip_runtime.h>
#include <type_traits>

typedef _Float16 f16;
typedef _Float16 f16x4 __attribute__((ext_vector_type(4)));
typedef _Float16 f16x8 __attribute__((ext_vector_type(8)));
typedef float    f32x4 __attribute__((ext_vector_type(4)));

constexpr int TT = 512;   // timesteps
constexpr int FF = 64;    // input features
constexpr int H1 = 128;   // layer-1 hidden (512 gate cols)
constexpr int H2 = 64;    // layer-2 hidden (256 gate cols)
constexpr int D1 = 25;    // dense-1 width
constexpr int S1 = 136;   // h1 LDS row stride (f16)
constexpr int S2 = 72;    // h2 LDS row stride
constexpr int XC = 8;     // x timesteps per staged LDS chunk (old path)
constexpr float L2E = 1.44269504088896f;

// z pre-scaled by log2(e) at weight-load time: sigmoid = rcp(1 + 2^-z).
__device__ __forceinline__ float sigm2(float z) {
    return __builtin_amdgcn_rcpf(1.f + __builtin_amdgcn_exp2f(-z));
}

__device__ __forceinline__ f32x4 mfma16(f16x8 a, f16x8 b, f32x4 c) {
    return __builtin_amdgcn_mfma_f32_16x16x32_f16(a, b, c, 0, 0, 0);
}

__device__ __forceinline__ void gl_lds16(const f16* g, f16* l) {
    __builtin_amdgcn_global_load_lds(
        (const __attribute__((address_space(1))) unsigned int*)g,
        (__attribute__((address_space(3))) unsigned int*)l, 16, 0, 0);
}

// ---------------------------------------------------------------------------
// NEW PATH (ws >= 256 MiB): precompute xw[b][t][512] = (x@W1 + b1)*gate_scale
// in f16 on the FULL GPU, so the 32-CU serial recurrence kernel drops the
// W1*x MFMAs (24 -> 16 per L1 wave-step) and all x staging.
// ---------------------------------------------------------------------------

// 2048 blocks x 512 threads; block handles 128 (b,t) rows x all 512 gate cols.
// Memory-bound: writes 256 MB f16. Weights staged transposed in LDS (f16,
// pre-scaled), bias pre-scaled in LDS, MFMA with weights as A operand =>
// D[m=4 consecutive gate cols][n=row] -> packed 8B stores.
__global__ __launch_bounds__(512)
void prep_xw(const float* __restrict__ x, const float* __restrict__ W1,
             const float* __restrict__ b1, f16* __restrict__ xw)
{
    __shared__ __align__(16) f16 wlds[512][72];   // [col][k], padded stride
    __shared__ __align__(16) float blds[512];
    const int tid = threadIdx.x;

    // stage W1^T (f16, gate-scaled): coalesced global reads, one-time LDS cost
    for (int idx = tid; idx < 64 * 512; idx += 512) {
        const int k = idx >> 9, col = idx & 511;
        const float sc = ((col >> 7) == 2) ? 1.f : L2E;
        wlds[col][k] = (f16)(W1[idx] * sc);
    }
    blds[tid] = b1[tid] * (((tid >> 7) == 2) ? 1.f : L2E);
    __syncthreads();

    const int wv = tid >> 6, lane = tid & 63, quad = lane >> 4, lid = lane & 15;
    const int row = blockIdx.x * 128 + wv * 16 + lid;   // flat (b*T + t) row

    // x fragment (B operand): lane holds x[row][k=32c+quad*8+e], f32 -> f16
    f16x8 xf[2];
#pragma unroll
    for (int c = 0; c < 2; ++c) {
        const float4 v0 = *(const float4*)(x + (size_t)row * FF + 32 * c + quad * 8);
        const float4 v1 = *(const float4*)(x + (size_t)row * FF + 32 * c + quad * 8 + 4);
        f16x8 f;
        f[0] = (f16)v0.x; f[1] = (f16)v0.y; f[2] = (f16)v0.z; f[3] = (f16)v0.w;
        f[4] = (f16)v1.x; f[5] = (f16)v1.y; f[6] = (f16)v1.z; f[7] = (f16)v1.w;
        xf[c] = f;
    }

#pragma unroll 4
    for (int cg = 0; cg < 32; ++cg) {
        const f16* wp = &wlds[16 * cg + lid][0];
        const f16x8 a0 = *(const f16x8*)(wp + quad * 8);        // k = 0..31
        const f16x8 a1 = *(const f16x8*)(wp + 32 + quad * 8);   // k = 32..63
        const f32x4 bv = *(const f32x4*)&blds[16 * cg + quad * 4];
        f32x4 acc = mfma16(a0, xf[0], bv);
        acc = mfma16(a1, xf[1], acc);
        f16x4 o;
#pragma unroll
        for (int r = 0; r < 4; ++r) o[r] = (f16)acc[r];
        *(f16x4*)&xw[(size_t)row * 512 + 16 * cg + quad * 4] = o;
    }
}

// Recurrence kernel, xw-fed. Same pipeline structure as R14 (32 blocks x 768
// threads, waves 0-7 = L1 step i, waves 8-11 = L2 step i-1, ping-pong LDS,
// one barrier per step, s_setprio 1 on L1). L1 MFMA chain is now 4 deep with
// C-init = cvt(xw). xw is register-prefetched TWO steps ahead via pair
// rotation over a 4-step unroll, so every outstanding global load is >= 1
// full step old at each barrier's implicit vmcnt(0) drain (R13's per-step
// load poison was zero-lead drain stalls -- avoided by construction).
__global__ __launch_bounds__(768, 3)
void lstm_pipe12_xw(const f16* __restrict__ xw, const float* __restrict__ U1,
                    const float* __restrict__ W2, const float* __restrict__ U2,
                    const float* __restrict__ b2, const float* __restrict__ Wd1,
                    const float* __restrict__ bd1,const float* __restrict__ Wd2,
                    const float* __restrict__ bd2, float* __restrict__ out)
{
    const int tid  = threadIdx.x;
    const int w    = tid >> 6;      // wave 0..11
    const int lane = tid & 63;
    const int quad = lane >> 4;
    const int lid  = lane & 15;
    const int b0   = blockIdx.x * 16;
    const bool isL1 = (w < 8);
    const int  j    = isL1 ? w : (w - 8);

    __shared__ __align__(16) f16 h1b[2][16][S1];
    __shared__ __align__(16) f16 h2b[2][16][S2];
    __shared__ float h2f[16][H2];
    __shared__ float dsh[16][D1];

    for (int i = tid; i < 2 * 16 * S1 / 2; i += 768) ((unsigned*)h1b)[i] = 0u;
    for (int i = tid; i < 2 * 16 * S2 / 2; i += 768) ((unsigned*)h2b)[i] = 0u;

    // ---- weight fragments wt[g][c] (A operand): lane holds col n=base+lid,
    // rows k = 32c + quad*8 + e. gates 0,1,3 (i,f,o) pre-scaled by log2e.
    // L1 (w<8):  chunks 0..3 = U1 (h1, K=128)          (x part is in xw)
    // L2 (w>=8): chunks 0..3 = W2 (h1, K=128), 4..5 = U2 (h2, K=64)
    f16x8 wt[4][6];
    f32x4 bsp[4];     // bias C-init (L2 only; L1 bias folded into xw)
    float cs[4] = {0.f, 0.f, 0.f, 0.f};

    if (isL1) {
#pragma unroll
        for (int g = 0; g < 4; ++g) {
            const float sc = (g == 2) ? 1.f : L2E;
            const int n = 128 * g + 16 * w + lid;
#pragma unroll
            for (int c = 0; c < 4; ++c) {
                f16x8 f;
#pragma unroll
                for (int e = 0; e < 8; ++e)
                    f[e] = (f16)(U1[(32 * c + quad * 8 + e) * 512 + n] * sc);
                wt[g][c] = f;
            }
        }
    } else {
#pragma unroll
        for (int g = 0; g < 4; ++g) {
            const float sc = (g == 2) ? 1.f : L2E;
            const int n = 64 * g + 16 * j + lid;
#pragma unroll
            for (int rr = 0; rr < 4; ++rr)
                bsp[g][rr] = b2[64 * g + 16 * j + quad * 4 + rr] * sc;
#pragma unroll
            for (int c = 0; c < 4; ++c) {
                f16x8 f;
#pragma unroll
                for (int e = 0; e < 8; ++e)
                    f[e] = (f16)(W2[(32 * c + quad * 8 + e) * 256 + n] * sc);
                wt[g][c] = f;
            }
#pragma unroll
            for (int c = 0; c < 2; ++c) {
                f16x8 f;
#pragma unroll
                for (int e = 0; e < 8; ++e)
                    f[e] = (f16)(U2[(32 * c + quad * 8 + e) * 256 + n] * sc);
                wt[g][4 + c] = f;
            }
        }
    }

    // per-lane xw base: batch row b0+lid, cols 16w+quad*4 (+128g per gate)
    const f16* pxw = nullptr;
    if (isL1) pxw = xw + (size_t)(b0 + lid) * TT * 512 + 16 * w + quad * 4;

    // xw register double-pair: xa = steps (4k, 4k+1), xb = steps (4k+2, 4k+3)
    f16x4 xa[2][4], xb[2][4];
    if (isL1) {
#pragma unroll
        for (int g = 0; g < 4; ++g) {
            xa[0][g] = *(const f16x4*)(pxw + (size_t)0 * 512 + 128 * g);
            xa[1][g] = *(const f16x4*)(pxw + (size_t)1 * 512 + 128 * g);
        }
    }
    __syncthreads();   // drains prologue loads

    // bias issue arbitration toward the serial L1 recurrence
    if (isL1) asm volatile("s_setprio 1");

    // one pipeline step; PAR = i&1 known at compile time => LDS immediates.
    // D[m=quad*4+r][n=lid]: m = 4 consecutive gate cols, n = batch row.
    auto step = [&](auto parc, int i, const f16x4 (&xv)[4]) {
        constexpr int PAR = decltype(parc)::value;
        constexpr int PR = PAR ^ 1;   // h1[i-1]
        constexpr int PW = PAR;       // h1[i]
        constexpr int QR = PAR;       // h2[i-2]
        constexpr int QW = PAR ^ 1;   // h2[i-1]
        if (isL1) {
            f16x8 fr0 = *(const f16x8*)&h1b[PR][lid][quad * 8];
            f16x8 fr1 = *(const f16x8*)&h1b[PR][lid][32 + quad * 8];
            f16x8 fr2 = *(const f16x8*)&h1b[PR][lid][64 + quad * 8];
            f16x8 fr3 = *(const f16x8*)&h1b[PR][lid][96 + quad * 8];
            f32x4 acc[4];
#pragma unroll
            for (int g = 0; g < 4; ++g) {
                f32x4 ci;
#pragma unroll
                for (int r = 0; r < 4; ++r) ci[r] = (float)xv[g][r];
                f32x4 a = mfma16(wt[g][0], fr0, ci);   // C-init = xw (bias in)
                a = mfma16(wt[g][1], fr1, a);
                a = mfma16(wt[g][2], fr2, a);
                a = mfma16(wt[g][3], fr3, a);
                acc[g] = a;
            }
            f16x4 hp;
#pragma unroll
            for (int r = 0; r < 4; ++r) {
                const float ig = sigm2(acc[0][r]);
                const float fg = sigm2(acc[1][r]);
                const float gg = fmaxf(acc[2][r], 0.f);
                const float og = sigm2(acc[3][r]);
                const float cc = fg * cs[r] + ig * gg;
                cs[r] = cc;
                hp[r] = (f16)(og * fmaxf(cc, 0.f));
            }
            *(f16x4*)&h1b[PW][lid][16 * w + quad * 4] = hp;   // packed b64
        } else {
            if (i >= 1) {
                f16x8 fr0 = *(const f16x8*)&h1b[PR][lid][quad * 8];
                f16x8 fr1 = *(const f16x8*)&h1b[PR][lid][32 + quad * 8];
                f16x8 fr2 = *(const f16x8*)&h1b[PR][lid][64 + quad * 8];
                f16x8 fr3 = *(const f16x8*)&h1b[PR][lid][96 + quad * 8];
                f16x8 fr4 = *(const f16x8*)&h2b[QR][lid][quad * 8];
                f16x8 fr5 = *(const f16x8*)&h2b[QR][lid][32 + quad * 8];
                f32x4 acc[4];
#pragma unroll
                for (int g = 0; g < 4; ++g) {
                    f32x4 a = mfma16(wt[g][0], fr0, bsp[g]);
                    a = mfma16(wt[g][1], fr1, a);
                    a = mfma16(wt[g][2], fr2, a);
                    a = mfma16(wt[g][3], fr3, a);
                    a = mfma16(wt[g][4], fr4, a);
                    a = mfma16(wt[g][5], fr5, a);
                    acc[g] = a;
                }
                f16x4 hp;
#pragma unroll
                for (int r = 0; r < 4; ++r) {
                    const float ig = sigm2(acc[0][r]);
                    const float fg = sigm2(acc[1][r]);
                    const float gg = fmaxf(acc[2][r], 0.f);
                    const float og = sigm2(acc[3][r]);
                    const float cc = fg * cs[r] + ig * gg;
                    cs[r] = cc;
                    hp[r] = (f16)(og * fmaxf(cc, 0.f));
                }
                *(f16x4*)&h2b[QW][lid][16 * j + quad * 4] = hp;   // packed b64
            }
        }
    };

    // ---- main loop, unrolled x4: ONE barrier per step; xw loads issued at
    // body-half starts so each is >= 1 step old at the barrier vmcnt drain.
    for (int ii = 0; ii < TT; ii += 4) {
        if (isL1) {   // pairB <- steps ii+2, ii+3 (consumed after 2 barriers)
#pragma unroll
            for (int g = 0; g < 4; ++g) {
                xb[0][g] = *(const f16x4*)(pxw + (size_t)(ii + 2) * 512 + 128 * g);
                xb[1][g] = *(const f16x4*)(pxw + (size_t)(ii + 3) * 512 + 128 * g);
            }
        }
        step(std::integral_constant<int, 0>{}, ii, xa[0]);
        __syncthreads();
        step(std::integral_constant<int, 1>{}, ii + 1, xa[1]);
        __syncthreads();
        if (isL1 && ii + 4 < TT) {   // pairA <- steps ii+4, ii+5
#pragma unroll
            for (int g = 0; g < 4; ++g) {
                xa[0][g] = *(const f16x4*)(pxw + (size_t)(ii + 4) * 512 + 128 * g);
                xa[1][g] = *(const f16x4*)(pxw + (size_t)(ii + 5) * 512 + 128 * g);
            }
        }
        step(std::integral_constant<int, 0>{}, ii + 2, xb[0]);
        __syncthreads();
        step(std::integral_constant<int, 1>{}, ii + 3, xb[1]);
        __syncthreads();
    }

    if (isL1) asm volatile("s_setprio 0");

    // final pipeline step i=TT (even): L2 consumes h1[TT-1], exports h2 f32
    if (!isL1) {
        f16x8 fr0 = *(const f16x8*)&h1b[1][lid][quad * 8];
        f16x8 fr1 = *(const f16x8*)&h1b[1][lid][32 + quad * 8];
        f16x8 fr2 = *(const f16x8*)&h1b[1][lid][64 + quad * 8];
        f16x8 fr3 = *(const f16x8*)&h1b[1][lid][96 + quad * 8];
        f16x8 fr4 = *(const f16x8*)&h2b[0][lid][quad * 8];
        f16x8 fr5 = *(const f16x8*)&h2b[0][lid][32 + quad * 8];
        f32x4 acc[4];
#pragma unroll
        for (int g = 0; g < 4; ++g) {
            f32x4 a = mfma16(wt[g][0], fr0, bsp[g]);
            a = mfma16(wt[g][1], fr1, a);
            a = mfma16(wt[g][2], fr2, a);
            a = mfma16(wt[g][3], fr3, a);
            a = mfma16(wt[g][4], fr4, a);
            a = mfma16(wt[g][5], fr5, a);
            acc[g] = a;
        }
        float4 ho;
#pragma unroll
        for (int r = 0; r < 4; ++r) {
            const float ig = sigm2(acc[0][r]);
            const float fg = sigm2(acc[1][r]);
            const float gg = fmaxf(acc[2][r], 0.f);
            const float og = sigm2(acc[3][r]);
            const float cc = fg * cs[r] + ig * gg;
            (&ho.x)[r] = og * fmaxf(cc, 0.f);
        }
        *(float4*)&h2f[lid][16 * j + quad * 4] = ho;   // [batch][unit]
    }
    __syncthreads();

    // ---------------- dense head ----------------
    for (int idx = tid; idx < 16 * D1; idx += 768) {
        const int bq = idx / D1, p = idx % D1;
        float d = bd1[p];
#pragma unroll
        for (int k = 0; k < H2; ++k) d += h2f[bq][k] * Wd1[k * D1 + p];
        dsh[bq][p] = d * Wd2[p];
    }
    __syncthreads();
    if (tid < 16) {
        float o = bd2[0];
#pragma unroll
        for (int p = 0; p < D1; ++p) o += dsh[tid][p];
        out[b0 + tid] = o;
    }
}

// ---------------------------------------------------------------------------
// OLD PATH (fallback, byte-identical R14 structure): used when ws_size cannot
// hold the 256 MiB xw buffer. Measured 680.7 us / kernel 583 us.
// ---------------------------------------------------------------------------

// pre-pass: x fp32 -> f16 so staging is a raw byte copy.
__global__ void cvt_x_kernel(const float* __restrict__ x, f16* __restrict__ xh) {
    const size_t i = ((size_t)blockIdx.x * blockDim.x + threadIdx.x) * 4;
    const float4 v = *(const float4*)(x + i);
    f16x4 h; h[0] = (f16)v.x; h[1] = (f16)v.y; h[2] = (f16)v.z; h[3] = (f16)v.w;
    *(f16x4*)(xh + i) = h;
}

__global__ __launch_bounds__(768, 3)
void lstm_pipe12(const f16* __restrict__ xh, const float* __restrict__ W1,
                 const float* __restrict__ U1, const float* __restrict__ b1,
                 const float* __restrict__ W2, const float* __restrict__ U2,
                 const float* __restrict__ b2, const float* __restrict__ Wd1,
                 const float* __restrict__ bd1,const float* __restrict__ Wd2,
                 const float* __restrict__ bd2, float* __restrict__ out)
{
    const int tid  = threadIdx.x;
    const int w    = tid >> 6;      // wave 0..11
    const int lane = tid & 63;
    const int quad = lane >> 4;
    const int lid  = lane & 15;
    const int b0   = blockIdx.x * 16;
    const bool isL1 = (w < 8);
    const int  j    = isL1 ? w : (w - 8);

    __shared__ __align__(16) f16 h1b[2][16][S1];
    __shared__ __align__(16) f16 h2b[2][16][S2];
    __shared__ __align__(16) f16 xlds[2][XC * 8 * 16 * 8];
    __shared__ float h2f[16][H2];
    __shared__ float dsh[16][D1];

    for (int i = tid; i < 2 * 16 * S1 / 2; i += 768) ((unsigned*)h1b)[i] = 0u;
    for (int i = tid; i < 2 * 16 * S2 / 2; i += 768) ((unsigned*)h2b)[i] = 0u;

    for (int s = tid; s < XC * 8 * 16; s += 768) {
        const int tl = s >> 7, fs = (s >> 4) & 7, row = s & 15;
        const f16* gp = xh + ((size_t)(b0 + row) * TT + tl) * FF + fs * 8;
        gl_lds16(gp, &xlds[0][(s >> 6) * 512]);
    }

    f16x8 wt[4][6];
    f32x4 bsp[4];
    float cs[4] = {0.f, 0.f, 0.f, 0.f};

    if (isL1) {
#pragma unroll
        for (int g = 0; g < 4; ++g) {
            const float sc = (g == 2) ? 1.f : L2E;
            const int n = 128 * g + 16 * w + lid;
#pragma unroll
            for (int rr = 0; rr < 4; ++rr)
                bsp[g][rr] = b1[128 * g + 16 * w + quad * 4 + rr] * sc;
#pragma unroll
            for (int c = 0; c < 4; ++c) {
                f16x8 f;
#pragma unroll
                for (int e = 0; e < 8; ++e)
                    f[e] = (f16)(U1[(32 * c + quad * 8 + e) * 512 + n] * sc);
                wt[g][c] = f;
            }
#pragma unroll
            for (int c = 0; c < 2; ++c) {
                f16x8 f;
#pragma unroll
                for (int e = 0; e < 8; ++e)
                    f[e] = (f16)(W1[(32 * c + quad * 8 + e) * 512 + n] * sc);
                wt[g][4 + c] = f;
            }
        }
    } else {
#pragma unroll
        for (int g = 0; g < 4; ++g) {
            const float sc = (g == 2) ? 1.f : L2E;
            const int n = 64 * g + 16 * j + lid;
#pragma unroll
            for (int rr = 0; rr < 4; ++rr)
                bsp[g][rr] = b2[64 * g + 16 * j + quad * 4 + rr] * sc;
#pragma unroll
            for (int c = 0; c < 4; ++c) {
                f16x8 f;
#pragma unroll
                for (int e = 0; e < 8; ++e)
                    f[e] = (f16)(W2[(32 * c + quad * 8 + e) * 256 + n] * sc);
                wt[g][c] = f;
            }
#pragma unroll
            for (int c = 0; c < 2; ++c) {
                f16x8 f;
#pragma unroll
                for (int e = 0; e < 8; ++e)
                    f[e] = (f16)(U2[(32 * c + quad * 8 + e) * 256 + n] * sc);
                wt[g][4 + c] = f;
            }
        }
    }
    __syncthreads();

    if (isL1) asm volatile("s_setprio 1");

    auto step = [&](auto parc, int i) {
        constexpr int PAR = decltype(parc)::value;
        constexpr int PR = PAR ^ 1;
        constexpr int PW = PAR;
        constexpr int QR = PAR;
        constexpr int QW = PAR ^ 1;
        if (isL1) {
            const f16* xc = &xlds[(i >> 3) & 1][(i & 7) * 1024];
            f16x8 fr0 = *(const f16x8*)&h1b[PR][lid][quad * 8];
            f16x8 fr1 = *(const f16x8*)&h1b[PR][lid][32 + quad * 8];
            f16x8 fr2 = *(const f16x8*)&h1b[PR][lid][64 + quad * 8];
            f16x8 fr3 = *(const f16x8*)&h1b[PR][lid][96 + quad * 8];
            f16x8 xf0 = *(const f16x8*)&xc[(quad * 16 + lid) * 8];
            f16x8 xf1 = *(const f16x8*)&xc[((4 + quad) * 16 + lid) * 8];
            f32x4 acc[4];
#pragma unroll
            for (int g = 0; g < 4; ++g) {
                f32x4 a = mfma16(wt[g][0], fr0, bsp[g]);
                a = mfma16(wt[g][1], fr1, a);
                a = mfma16(wt[g][2], fr2, a);
                a = mfma16(wt[g][3], fr3, a);
                a = mfma16(wt[g][4], xf0, a);
                a = mfma16(wt[g][5], xf1, a);
                acc[g] = a;
            }
            f16x4 hp;
#pragma unroll
            for (int r = 0; r < 4; ++r) {
                const float ig = sigm2(acc[0][r]);
                const float fg = sigm2(acc[1][r]);
                const float gg = fmaxf(acc[2][r], 0.f);
                const float og = sigm2(acc[3][r]);
                const float cc = fg * cs[r] + ig * gg;
                cs[r] = cc;
                hp[r] = (f16)(og * fmaxf(cc, 0.f));
            }
            *(f16x4*)&h1b[PW][lid][16 * w + quad * 4] = hp;
        } else {
            if (i >= 1) {
                f16x8 fr0 = *(const f16x8*)&h1b[PR][lid][quad * 8];
                f16x8 fr1 = *(const f16x8*)&h1b[PR][lid][32 + quad * 8];
                f16x8 fr2 = *(const f16x8*)&h1b[PR][lid][64 + quad * 8];
                f16x8 fr3 = *(const f16x8*)&h1b[PR][lid][96 + quad * 8];
                f16x8 fr4 = *(const f16x8*)&h2b[QR][lid][quad * 8];
                f16x8 fr5 = *(const f16x8*)&h2b[QR][lid][32 + quad * 8];
                f32x4 acc[4];
#pragma unroll
                for (int g = 0; g < 4; ++g) {
                    f32x4 a = mfma16(wt[g][0], fr0, bsp[g]);
                    a = mfma16(wt[g][1], fr1, a);
                    a = mfma16(wt[g][2], fr2, a);
                    a = mfma16(wt[g][3], fr3, a);
                    a = mfma16(wt[g][4], fr4, a);
                    a = mfma16(wt[g][5], fr5, a);
                    acc[g] = a;
                }
                f16x4 hp;
#pragma unroll
                for (int r = 0; r < 4; ++r) {
                    const float ig = sigm2(acc[0][r]);
                    const float fg = sigm2(acc[1][r]);
                    const float gg = fmaxf(acc[2][r], 0.f);
                    const float og = sigm2(acc[3][r]);
                    const float cc = fg * cs[r] + ig * gg;
                    cs[r] = cc;
                    hp[r] = (f16)(og * fmaxf(cc, 0.f));
                }
                *(f16x4*)&h2b[QW][lid][16 * j + quad * 4] = hp;
            }
        }
    };

    for (int ii = 0; ii < TT; ii += 2) {
        if ((ii & (XC - 1)) == 0 && ii + XC < TT) {
            const int nc = (ii >> 3) + 1;
            f16* dst = xlds[nc & 1];
            for (int s = tid; s < XC * 8 * 16; s += 768) {
                const int tl = s >> 7, fs = (s >> 4) & 7, row = s & 15;
                const f16* gp = xh + ((size_t)(b0 + row) * TT + (nc * XC + tl)) * FF + fs * 8;
                gl_lds16(gp, &dst[(s >> 6) * 512]);
            }
        }
        step(std::integral_constant<int, 0>{}, ii);
        __syncthreads();
        step(std::integral_constant<int, 1>{}, ii + 1);
        __syncthreads();
    }

    if (isL1) asm volatile("s_setprio 0");

    if (!isL1) {
        f16x8 fr0 = *(const f16x8*)&h1b[1][lid][quad * 8];
        f16x8 fr1 = *(const f16x8*)&h1b[1][lid][32 + quad * 8];
        f16x8 fr2 = *(const f16x8*)&h1b[1][lid][64 + quad * 8];
        f16x8 fr3 = *(const f16x8*)&h1b[1][lid][96 + quad * 8];
        f16x8 fr4 = *(const f16x8*)&h2b[0][lid][quad * 8];
        f16x8 fr5 = *(const f16x8*)&h2b[0][lid][32 + quad * 8];
        f32x4 acc[4];
#pragma unroll
        for (int g = 0; g < 4; ++g) {
            f32x4 a = mfma16(wt[g][0], fr0, bsp[g]);
            a = mfma16(wt[g][1], fr1, a);
            a = mfma16(wt[g][2], fr2, a);
            a = mfma16(wt[g][3], fr3, a);
            a = mfma16(wt[g][4], fr4, a);
            a = mfma16(wt[g][5], fr5, a);
            acc[g] = a;
        }
        float4 ho;
#pragma unroll
        for (int r = 0; r < 4; ++r) {
            const float ig = sigm2(acc[0][r]);
            const float fg = sigm2(acc[1][r]);
            const float gg = fmaxf(acc[2][r], 0.f);
            const float og = sigm2(acc[3][r]);
            const float cc = fg * cs[r] + ig * gg;
            (&ho.x)[r] = og * fmaxf(cc, 0.f);
        }
        *(float4*)&h2f[lid][16 * j + quad * 4] = ho;
    }
    __syncthreads();

    for (int idx = tid; idx < 16 * D1; idx += 768) {
        const int bq = idx / D1, p = idx % D1;
        float d = bd1[p];
#pragma unroll
        for (int k = 0; k < H2; ++k) d += h2f[bq][k] * Wd1[k * D1 + p];
        dsh[bq][p] = d * Wd2[p];
    }
    __syncthreads();
    if (tid < 16) {
        float o = bd2[0];
#pragma unroll
        for (int p = 0; p < D1; ++p) o += dsh[tid][p];
        out[b0 + tid] = o;
    }
}

extern "C" void kernel_launch(void* const* d_in, const int* in_sizes, int n_in,
                              void* d_out, int out_size, void* d_ws, size_t ws_size,
                              hipStream_t stream) {
    (void)in_sizes; (void)n_in; (void)out_size;
    const float* x   = (const float*)d_in[0];
    const float* W1  = (const float*)d_in[1];
    const float* U1  = (const float*)d_in[2];
    const float* b1  = (const float*)d_in[3];
    const float* W2  = (const float*)d_in[4];
    const float* U2  = (const float*)d_in[5];
    const float* b2  = (const float*)d_in[6];
    const float* Wd1 = (const float*)d_in[7];
    const float* bd1 = (const float*)d_in[8];
    const float* Wd2 = (const float*)d_in[9];
    const float* bd2 = (const float*)d_in[10];
    float* out = (float*)d_out;

    constexpr size_t XW_BYTES = (size_t)512 * 512 * 512 * sizeof(f16);  // 256 MiB

    if (ws_size >= XW_BYTES) {
        // NEW PATH: full-GPU x-projection precompute + leaner recurrence
        f16* xwp = (f16*)d_ws;
        prep_xw<<<dim3(2048), dim3(512), 0, stream>>>(x, W1, b1, xwp);
        lstm_pipe12_xw<<<dim3(32), dim3(768), 0, stream>>>(
            xwp, U1, W2, U2, b2, Wd1, bd1, Wd2, bd2, out);
    } else {
        // FALLBACK: R14 path (f16 x staging in 32 MiB workspace)
        f16* xh = (f16*)d_ws;
        const int nx = 512 * 512 * 64;
        cvt_x_kernel<<<dim3(nx / (256 * 4)), dim3(256), 0, stream>>>(x, xh);
        lstm_pipe12<<<dim3(32), dim3(768), 0, stream>>>(
            xh, W1, U1, b1, W2, U2, b2, Wd1, bd1, Wd2, bd2, out);
    }
}

// Round 2
// 1248.022 us; speedup vs baseline: 1.1884x; 1.1884x over previous
//
#include <hip/hip_runtime.h>
#include <type_traits>

typedef _Float16 f16;
typedef _Float16 f16x4 __attribute__((ext_vector_type(4)));
typedef _Float16 f16x8 __attribute__((ext_vector_type(8)));
typedef float    f32x4 __attribute__((ext_vector_type(4)));

constexpr int TT = 512;   // timesteps
constexpr int FF = 64;    // input features
constexpr int H1 = 128;   // layer-1 hidden (512 gate cols)
constexpr int H2 = 64;    // layer-2 hidden (256 gate cols)
constexpr int D1 = 25;    // dense-1 width
constexpr int S1 = 136;   // h1 LDS row stride (f16)
constexpr int S2 = 72;    // h2 LDS row stride
constexpr int XC = 8;     // x timesteps per staged LDS chunk
constexpr float L2E = 1.44269504088896f;

// z pre-scaled by log2(e) at weight-load time: sigmoid = rcp(1 + 2^-z).
__device__ __forceinline__ float sigm2(float z) {
    return __builtin_amdgcn_rcpf(1.f + __builtin_amdgcn_exp2f(-z));
}

__device__ __forceinline__ f32x4 mfma16(f16x8 a, f16x8 b, f32x4 c) {
    return __builtin_amdgcn_mfma_f32_16x16x32_f16(a, b, c, 0, 0, 0);
}

__device__ __forceinline__ void gl_lds16(const f16* g, f16* l) {
    __builtin_amdgcn_global_load_lds(
        (const __attribute__((address_space(1))) unsigned int*)g,
        (__attribute__((address_space(3))) unsigned int*)l, 16, 0, 0);
}

// pre-pass: x fp32 -> f16 so staging is a raw byte copy.
__global__ void cvt_x_kernel(const float* __restrict__ x, f16* __restrict__ xh) {
    const size_t i = ((size_t)blockIdx.x * blockDim.x + threadIdx.x) * 4;
    const float4 v = *(const float4*)(x + i);
    f16x4 h; h[0] = (f16)v.x; h[1] = (f16)v.y; h[2] = (f16)v.z; h[3] = (f16)v.w;
    *(f16x4*)(xh + i) = h;
}

// R16 = R14 (583 us kernel, best passing) + two critical-chain shortenings:
//  (1) L1 x-contribution decoupled: czx[g] = W1x*x[i+1] + b1 is computed
//      DURING step i (x does not depend on h), so step i's dependent chain
//      is 4 MFMAs (U-chunks from in-register C=czx) instead of 6. The two
//      x-MFMAs are latency-off-path and fill the epilogue window. Same MFMA
//      count; FP accumulation order changes only (bias,x first, then U).
//  (2) L2 accumulation split into two parallel 3-chains + f32x4 add:
//      dependency depth 6 -> 3 (+1 VALU add). L2 waves are co-critical
//      (every barrier waits for the slowest wave).
// Structure otherwise identical: 32 blocks x 768 threads (12 waves, 3/SIMD),
// waves 0-7 = L1 step i, waves 8-11 = L2 step i-1, ping-pong h1/h2 LDS,
// ONE barrier per step, x double-buffered in LDS via global_load_lds every
// 8 steps (drain amortized; per-step global loads are poison -- R13/R15).
__global__ __launch_bounds__(768, 3)
void lstm_pipe12(const f16* __restrict__ xh, const float* __restrict__ W1,
                 const float* __restrict__ U1, const float* __restrict__ b1,
                 const float* __restrict__ W2, const float* __restrict__ U2,
                 const float* __restrict__ b2, const float* __restrict__ Wd1,
                 const float* __restrict__ bd1,const float* __restrict__ Wd2,
                 const float* __restrict__ bd2, float* __restrict__ out)
{
    const int tid  = threadIdx.x;
    const int w    = tid >> 6;      // wave 0..11
    const int lane = tid & 63;
    const int quad = lane >> 4;
    const int lid  = lane & 15;
    const int b0   = blockIdx.x * 16;
    const bool isL1 = (w < 8);
    const int  j    = isL1 ? w : (w - 8);

    __shared__ __align__(16) f16 h1b[2][16][S1];
    __shared__ __align__(16) f16 h2b[2][16][S2];
    // x chunk layout: [tl(8)][fseg(8)][row(16)] of 8-f16 (16 B) segments.
    __shared__ __align__(16) f16 xlds[2][XC * 8 * 16 * 8];
    __shared__ float h2f[16][H2];
    __shared__ float dsh[16][D1];

    for (int i = tid; i < 2 * 16 * S1 / 2; i += 768) ((unsigned*)h1b)[i] = 0u;
    for (int i = tid; i < 2 * 16 * S2 / 2; i += 768) ((unsigned*)h2b)[i] = 0u;

    // stage x chunk 0 (timesteps 0..7) into xlds[0]
    for (int s = tid; s < XC * 8 * 16; s += 768) {
        const int tl = s >> 7, fs = (s >> 4) & 7, row = s & 15;
        const f16* gp = xh + ((size_t)(b0 + row) * TT + tl) * FF + fs * 8;
        gl_lds16(gp, &xlds[0][(s >> 6) * 512]);
    }

    // ---- weight fragments wt[g][c] (A operand): lane holds col n=base+lid,
    // rows k = 32c + quad*8 + e. gates 0,1,3 (i,f,o) pre-scaled by log2e.
    // L1 (w<8):  chunks 0..3 = U1 (h1, K=128), 4..5 = W1 (x, K=64)
    // L2 (w>=8): chunks 0..3 = W2 (h1, K=128), 4..5 = U2 (h2, K=64)
    f16x8 wt[4][6];
    f32x4 bsp[4];     // bias for this lane's 4 consecutive gate cols (C-init)
    f32x4 czx[4];     // L1: W1x*x[i+1] + b1, computed one step ahead
    float cs[4] = {0.f, 0.f, 0.f, 0.f};

    if (isL1) {
#pragma unroll
        for (int g = 0; g < 4; ++g) {
            const float sc = (g == 2) ? 1.f : L2E;
            const int n = 128 * g + 16 * w + lid;
#pragma unroll
            for (int rr = 0; rr < 4; ++rr)
                bsp[g][rr] = b1[128 * g + 16 * w + quad * 4 + rr] * sc;
#pragma unroll
            for (int c = 0; c < 4; ++c) {
                f16x8 f;
#pragma unroll
                for (int e = 0; e < 8; ++e)
                    f[e] = (f16)(U1[(32 * c + quad * 8 + e) * 512 + n] * sc);
                wt[g][c] = f;
            }
#pragma unroll
            for (int c = 0; c < 2; ++c) {
                f16x8 f;
#pragma unroll
                for (int e = 0; e < 8; ++e)
                    f[e] = (f16)(W1[(32 * c + quad * 8 + e) * 512 + n] * sc);
                wt[g][4 + c] = f;
            }
        }
    } else {
#pragma unroll
        for (int g = 0; g < 4; ++g) {
            const float sc = (g == 2) ? 1.f : L2E;
            const int n = 64 * g + 16 * j + lid;
#pragma unroll
            for (int rr = 0; rr < 4; ++rr)
                bsp[g][rr] = b2[64 * g + 16 * j + quad * 4 + rr] * sc;
#pragma unroll
            for (int c = 0; c < 4; ++c) {
                f16x8 f;
#pragma unroll
                for (int e = 0; e < 8; ++e)
                    f[e] = (f16)(W2[(32 * c + quad * 8 + e) * 256 + n] * sc);
                wt[g][c] = f;
            }
#pragma unroll
            for (int c = 0; c < 2; ++c) {
                f16x8 f;
#pragma unroll
                for (int e = 0; e < 8; ++e)
                    f[e] = (f16)(U2[(32 * c + quad * 8 + e) * 256 + n] * sc);
                wt[g][4 + c] = f;
            }
        }
    }
    __syncthreads();   // also drains chunk-0 staging vmcnt

    // L1 prologue: czx for step 0 from x[0] (chunk 0), then bias issue
    // arbitration toward the serial L1 recurrence.
    if (isL1) {
        const f16* xc0 = &xlds[0][0];
        const f16x8 x0 = *(const f16x8*)&xc0[(quad * 16 + lid) * 8];
        const f16x8 x1 = *(const f16x8*)&xc0[((4 + quad) * 16 + lid) * 8];
#pragma unroll
        for (int g = 0; g < 4; ++g)
            czx[g] = mfma16(wt[g][5], x1, mfma16(wt[g][4], x0, bsp[g]));
        asm volatile("s_setprio 1");
    }

    // one pipeline step; PAR = i&1 known at compile time => LDS immediates.
    // D[m=quad*4+r][n=lid]: m = 4 consecutive gate cols, n = batch row.
    auto step = [&](auto parc, int i) {
        constexpr int PAR = decltype(parc)::value;
        constexpr int PR = PAR ^ 1;   // h1[i-1]
        constexpr int PW = PAR;       // h1[i]
        constexpr int QR = PAR;       // h2[i-2]
        constexpr int QW = PAR ^ 1;   // h2[i-1]
        if (isL1) {
            // x fragments for step i+1 (independent of h -> off critical path)
            const int ip = i + 1;
            const f16* xc1 = &xlds[(ip >> 3) & 1][(ip & 7) * 1024];
            f16x8 xn0 = *(const f16x8*)&xc1[(quad * 16 + lid) * 8];
            f16x8 xn1 = *(const f16x8*)&xc1[((4 + quad) * 16 + lid) * 8];
            f16x8 fr0 = *(const f16x8*)&h1b[PR][lid][quad * 8];
            f16x8 fr1 = *(const f16x8*)&h1b[PR][lid][32 + quad * 8];
            f16x8 fr2 = *(const f16x8*)&h1b[PR][lid][64 + quad * 8];
            f16x8 fr3 = *(const f16x8*)&h1b[PR][lid][96 + quad * 8];
            f32x4 acc[4];
#pragma unroll
            for (int g = 0; g < 4; ++g) {
                f32x4 a = mfma16(wt[g][0], fr0, czx[g]);   // C = bias + W1*x[i]
                a = mfma16(wt[g][1], fr1, a);
                a = mfma16(wt[g][2], fr2, a);
                a = mfma16(wt[g][3], fr3, a);
                acc[g] = a;
            }
            if (ip < TT) {   // czx for step i+1, fills the epilogue window
#pragma unroll
                for (int g = 0; g < 4; ++g)
                    czx[g] = mfma16(wt[g][5], xn1, mfma16(wt[g][4], xn0, bsp[g]));
            }
            f16x4 hp;
#pragma unroll
            for (int r = 0; r < 4; ++r) {
                const float ig = sigm2(acc[0][r]);
                const float fg = sigm2(acc[1][r]);
                const float gg = fmaxf(acc[2][r], 0.f);
                const float og = sigm2(acc[3][r]);
                const float cc = fg * cs[r] + ig * gg;
                cs[r] = cc;
                hp[r] = (f16)(og * fmaxf(cc, 0.f));
            }
            *(f16x4*)&h1b[PW][lid][16 * w + quad * 4] = hp;   // packed b64
        } else {
            if (i >= 1) {
                f16x8 fr0 = *(const f16x8*)&h1b[PR][lid][quad * 8];
                f16x8 fr1 = *(const f16x8*)&h1b[PR][lid][32 + quad * 8];
                f16x8 fr2 = *(const f16x8*)&h1b[PR][lid][64 + quad * 8];
                f16x8 fr3 = *(const f16x8*)&h1b[PR][lid][96 + quad * 8];
                f16x8 fr4 = *(const f16x8*)&h2b[QR][lid][quad * 8];
                f16x8 fr5 = *(const f16x8*)&h2b[QR][lid][32 + quad * 8];
                // two parallel 3-chains: dependency depth 6 -> 3 (+1 add)
                f32x4 za = {0.f, 0.f, 0.f, 0.f};
                f32x4 acc[4];
#pragma unroll
                for (int g = 0; g < 4; ++g) {
                    f32x4 a = mfma16(wt[g][0], fr0, bsp[g]);
                    a = mfma16(wt[g][1], fr1, a);
                    a = mfma16(wt[g][2], fr2, a);
                    f32x4 b_ = mfma16(wt[g][3], fr3, za);
                    b_ = mfma16(wt[g][4], fr4, b_);
                    b_ = mfma16(wt[g][5], fr5, b_);
                    acc[g] = a + b_;
                }
                f16x4 hp;
#pragma unroll
                for (int r = 0; r < 4; ++r) {
                    const float ig = sigm2(acc[0][r]);
                    const float fg = sigm2(acc[1][r]);
                    const float gg = fmaxf(acc[2][r], 0.f);
                    const float og = sigm2(acc[3][r]);
                    const float cc = fg * cs[r] + ig * gg;
                    cs[r] = cc;
                    hp[r] = (f16)(og * fmaxf(cc, 0.f));
                }
                *(f16x4*)&h2b[QW][lid][16 * j + quad * 4] = hp;   // packed b64
            }
        }
    };

    // ---------------- main loop, unrolled x2: ONE barrier per step ----------------
    for (int ii = 0; ii < TT; ii += 2) {
        if ((ii & (XC - 1)) == 0 && ii + XC < TT) {
            const int nc = (ii >> 3) + 1;
            f16* dst = xlds[nc & 1];
            for (int s = tid; s < XC * 8 * 16; s += 768) {
                const int tl = s >> 7, fs = (s >> 4) & 7, row = s & 15;
                const f16* gp = xh + ((size_t)(b0 + row) * TT + (nc * XC + tl)) * FF + fs * 8;
                gl_lds16(gp, &dst[(s >> 6) * 512]);
            }
        }
        step(std::integral_constant<int, 0>{}, ii);
        __syncthreads();
        step(std::integral_constant<int, 1>{}, ii + 1);
        __syncthreads();
    }

    if (isL1) asm volatile("s_setprio 0");

    // final pipeline step i=TT (even): L2 consumes h1[TT-1], exports h2 f32
    if (!isL1) {
        f16x8 fr0 = *(const f16x8*)&h1b[1][lid][quad * 8];
        f16x8 fr1 = *(const f16x8*)&h1b[1][lid][32 + quad * 8];
        f16x8 fr2 = *(const f16x8*)&h1b[1][lid][64 + quad * 8];
        f16x8 fr3 = *(const f16x8*)&h1b[1][lid][96 + quad * 8];
        f16x8 fr4 = *(const f16x8*)&h2b[0][lid][quad * 8];
        f16x8 fr5 = *(const f16x8*)&h2b[0][lid][32 + quad * 8];
        f32x4 acc[4];
#pragma unroll
        for (int g = 0; g < 4; ++g) {
            f32x4 a = mfma16(wt[g][0], fr0, bsp[g]);
            a = mfma16(wt[g][1], fr1, a);
            a = mfma16(wt[g][2], fr2, a);
            a = mfma16(wt[g][3], fr3, a);
            a = mfma16(wt[g][4], fr4, a);
            a = mfma16(wt[g][5], fr5, a);
            acc[g] = a;
        }
        float4 ho;
#pragma unroll
        for (int r = 0; r < 4; ++r) {
            const float ig = sigm2(acc[0][r]);
            const float fg = sigm2(acc[1][r]);
            const float gg = fmaxf(acc[2][r], 0.f);
            const float og = sigm2(acc[3][r]);
            const float cc = fg * cs[r] + ig * gg;
            (&ho.x)[r] = og * fmaxf(cc, 0.f);
        }
        *(float4*)&h2f[lid][16 * j + quad * 4] = ho;   // [batch][unit]
    }
    __syncthreads();

    // ---------------- dense head ----------------
    for (int idx = tid; idx < 16 * D1; idx += 768) {
        const int bq = idx / D1, p = idx % D1;
        float d = bd1[p];
#pragma unroll
        for (int k = 0; k < H2; ++k) d += h2f[bq][k] * Wd1[k * D1 + p];
        dsh[bq][p] = d * Wd2[p];
    }
    __syncthreads();
    if (tid < 16) {
        float o = bd2[0];
#pragma unroll
        for (int p = 0; p < D1; ++p) o += dsh[tid][p];
        out[b0 + tid] = o;
    }
}

extern "C" void kernel_launch(void* const* d_in, const int* in_sizes, int n_in,
                              void* d_out, int out_size, void* d_ws, size_t ws_size,
                              hipStream_t stream) {
    (void)in_sizes; (void)n_in; (void)out_size; (void)ws_size;
    const float* x   = (const float*)d_in[0];
    const float* W1  = (const float*)d_in[1];
    const float* U1  = (const float*)d_in[2];
    const float* b1  = (const float*)d_in[3];
    const float* W2  = (const float*)d_in[4];
    const float* U2  = (const float*)d_in[5];
    const float* b2  = (const float*)d_in[6];
    const float* Wd1 = (const float*)d_in[7];
    const float* bd1 = (const float*)d_in[8];
    const float* Wd2 = (const float*)d_in[9];
    const float* bd2 = (const float*)d_in[10];
    float* out = (float*)d_out;
    f16*   xh  = (f16*)d_ws;    // 512*512*64 f16 = 32 MiB scratch

    const int nx = 512 * 512 * 64;
    cvt_x_kernel<<<dim3(nx / (256 * 4)), dim3(256), 0, stream>>>(x, xh);
    lstm_pipe12<<<dim3(32), dim3(768), 0, stream>>>(
        xh, W1, U1, b1, W2, U2, b2, Wd1, bd1, Wd2, bd2, out);
}

// Round 3
// 1152.349 us; speedup vs baseline: 1.2871x; 1.0830x over previous
//
#include <hip/hip_runtime.h>
#include <type_traits>

typedef _Float16 f16;
typedef _Float16 f16x4 __attribute__((ext_vector_type(4)));
typedef _Float16 f16x8 __attribute__((ext_vector_type(8)));
typedef float    f32x4 __attribute__((ext_vector_type(4)));

constexpr int TT = 512;   // timesteps
constexpr int FF = 64;    // input features
constexpr int H1 = 128;   // layer-1 hidden (512 gate cols)
constexpr int H2 = 64;    // layer-2 hidden (256 gate cols)
constexpr int D1 = 25;    // dense-1 width
constexpr int S1 = 136;   // h1 LDS row stride (f16)
constexpr int S2 = 72;    // h2 LDS row stride
constexpr int XC = 8;     // x timesteps per staged LDS chunk
constexpr float L2E = 1.44269504088896f;

// z pre-scaled by log2(e) at weight-load time: sigmoid = rcp(1 + 2^-z).
__device__ __forceinline__ float sigm2(float z) {
    return __builtin_amdgcn_rcpf(1.f + __builtin_amdgcn_exp2f(-z));
}

__device__ __forceinline__ f32x4 mfma16(f16x8 a, f16x8 b, f32x4 c) {
    return __builtin_amdgcn_mfma_f32_16x16x32_f16(a, b, c, 0, 0, 0);
}

__device__ __forceinline__ void gl_lds16(const f16* g, f16* l) {
    __builtin_amdgcn_global_load_lds(
        (const __attribute__((address_space(1))) unsigned int*)g,
        (__attribute__((address_space(3))) unsigned int*)l, 16, 0, 0);
}

// pre-pass: x fp32 -> f16 so staging is a raw byte copy.
__global__ void cvt_x_kernel(const float* __restrict__ x, f16* __restrict__ xh) {
    const size_t i = ((size_t)blockIdx.x * blockDim.x + threadIdx.x) * 4;
    const float4 v = *(const float4*)(x + i);
    f16x4 h; h[0] = (f16)v.x; h[1] = (f16)v.y; h[2] = (f16)v.z; h[3] = (f16)v.w;
    *(f16x4*)(xh + i) = h;
}

// R17 = R14 (583 us kernel) + ONE change: L1 x-contribution decoupled.
//   czx[g] = W1x*x[i+1] + b1 is computed DURING step i (x independent of h),
//   so step i's dependent chain is 4 MFMAs (C-init = czx in-register) not 6.
//   Same MFMA issue count; only FP accumulation order changes.
// R16 post-mortem: the same idea regressed 2x because `if (ip < TT)` made the
// czx array-write conditional -> predicated phi across the lambda -> compiler
// demoted czx to SCRATCH (VGPR stayed 84; WRITE_SIZE 0.8->2.8 MB), putting an
// L2-latency scratch load at the head of every step's acc chain. Fix: czx is
// written UNCONDITIONALLY with masked index ip=(i+1)&511 (last-step value is
// stale-LDS garbage, never consumed) -- branch-free, register-resident like
// cs[4]. L2 waves: exact R14 body (R16's split-chain confound removed).
// Structure: 32 blocks x 768 threads (12 waves, 3/SIMD). Waves 0-7: layer-1
// step i. Waves 8-11: layer-2 step i-1. Ping-pong h1/h2 LDS => ONE barrier
// per step; compile-time parity; operand-swapped MFMA (weights = A operand).
// x double-buffered in LDS via global_load_lds every 8 steps.
__global__ __launch_bounds__(768, 3)
void lstm_pipe12(const f16* __restrict__ xh, const float* __restrict__ W1,
                 const float* __restrict__ U1, const float* __restrict__ b1,
                 const float* __restrict__ W2, const float* __restrict__ U2,
                 const float* __restrict__ b2, const float* __restrict__ Wd1,
                 const float* __restrict__ bd1,const float* __restrict__ Wd2,
                 const float* __restrict__ bd2, float* __restrict__ out)
{
    const int tid  = threadIdx.x;
    const int w    = tid >> 6;      // wave 0..11
    const int lane = tid & 63;
    const int quad = lane >> 4;
    const int lid  = lane & 15;
    const int b0   = blockIdx.x * 16;
    const bool isL1 = (w < 8);
    const int  j    = isL1 ? w : (w - 8);

    __shared__ __align__(16) f16 h1b[2][16][S1];
    __shared__ __align__(16) f16 h2b[2][16][S2];
    // x chunk layout: [tl(8)][fseg(8)][row(16)] of 8-f16 (16 B) segments.
    __shared__ __align__(16) f16 xlds[2][XC * 8 * 16 * 8];
    __shared__ float h2f[16][H2];
    __shared__ float dsh[16][D1];

    for (int i = tid; i < 2 * 16 * S1 / 2; i += 768) ((unsigned*)h1b)[i] = 0u;
    for (int i = tid; i < 2 * 16 * S2 / 2; i += 768) ((unsigned*)h2b)[i] = 0u;

    // stage x chunk 0 (timesteps 0..7) into xlds[0]
    for (int s = tid; s < XC * 8 * 16; s += 768) {
        const int tl = s >> 7, fs = (s >> 4) & 7, row = s & 15;
        const f16* gp = xh + ((size_t)(b0 + row) * TT + tl) * FF + fs * 8;
        gl_lds16(gp, &xlds[0][(s >> 6) * 512]);
    }

    // ---- weight fragments wt[g][c] (A operand): lane holds col n=base+lid,
    // rows k = 32c + quad*8 + e. gates 0,1,3 (i,f,o) pre-scaled by log2e.
    // L1 (w<8):  chunks 0..3 = U1 (h1, K=128), 4..5 = W1 (x, K=64)
    // L2 (w>=8): chunks 0..3 = W2 (h1, K=128), 4..5 = U2 (h2, K=64)
    f16x8 wt[4][6];
    f32x4 bsp[4];     // bias for this lane's 4 consecutive gate cols (C-init)
    f32x4 czx[4];     // L1: b1 + W1*x[i+1], computed one step ahead
    float cs[4] = {0.f, 0.f, 0.f, 0.f};

    if (isL1) {
#pragma unroll
        for (int g = 0; g < 4; ++g) {
            const float sc = (g == 2) ? 1.f : L2E;
            const int n = 128 * g + 16 * w + lid;
#pragma unroll
            for (int rr = 0; rr < 4; ++rr)
                bsp[g][rr] = b1[128 * g + 16 * w + quad * 4 + rr] * sc;
#pragma unroll
            for (int c = 0; c < 4; ++c) {
                f16x8 f;
#pragma unroll
                for (int e = 0; e < 8; ++e)
                    f[e] = (f16)(U1[(32 * c + quad * 8 + e) * 512 + n] * sc);
                wt[g][c] = f;
            }
#pragma unroll
            for (int c = 0; c < 2; ++c) {
                f16x8 f;
#pragma unroll
                for (int e = 0; e < 8; ++e)
                    f[e] = (f16)(W1[(32 * c + quad * 8 + e) * 512 + n] * sc);
                wt[g][4 + c] = f;
            }
        }
    } else {
#pragma unroll
        for (int g = 0; g < 4; ++g) {
            const float sc = (g == 2) ? 1.f : L2E;
            const int n = 64 * g + 16 * j + lid;
#pragma unroll
            for (int rr = 0; rr < 4; ++rr)
                bsp[g][rr] = b2[64 * g + 16 * j + quad * 4 + rr] * sc;
#pragma unroll
            for (int c = 0; c < 4; ++c) {
                f16x8 f;
#pragma unroll
                for (int e = 0; e < 8; ++e)
                    f[e] = (f16)(W2[(32 * c + quad * 8 + e) * 256 + n] * sc);
                wt[g][c] = f;
            }
#pragma unroll
            for (int c = 0; c < 2; ++c) {
                f16x8 f;
#pragma unroll
                for (int e = 0; e < 8; ++e)
                    f[e] = (f16)(U2[(32 * c + quad * 8 + e) * 256 + n] * sc);
                wt[g][4 + c] = f;
            }
        }
    }
    __syncthreads();   // also drains chunk-0 staging vmcnt

    // L1 prologue: czx for step 0 from x[0] (chunk 0), then bias issue
    // arbitration toward the serial L1 recurrence.
    if (isL1) {
        const f16* xc0 = &xlds[0][0];
        const f16x8 x0 = *(const f16x8*)&xc0[(quad * 16 + lid) * 8];
        const f16x8 x1 = *(const f16x8*)&xc0[((4 + quad) * 16 + lid) * 8];
#pragma unroll
        for (int g = 0; g < 4; ++g)
            czx[g] = mfma16(wt[g][5], x1, mfma16(wt[g][4], x0, bsp[g]));
        asm volatile("s_setprio 1");
    }

    // one pipeline step; PAR = i&1 known at compile time => LDS immediates.
    // D[m=quad*4+r][n=lid]: m = 4 consecutive gate cols, n = batch row.
    auto step = [&](auto parc, int i) {
        constexpr int PAR = decltype(parc)::value;
        constexpr int PR = PAR ^ 1;   // h1[i-1]
        constexpr int PW = PAR;       // h1[i]
        constexpr int QR = PAR;       // h2[i-2]
        constexpr int QW = PAR ^ 1;   // h2[i-1]
        if (isL1) {
            // x fragments for step i+1 (independent of h -> off critical
            // path). Masked index: at i=511 this reads stale in-bounds LDS;
            // the resulting czx is never consumed. Branch-free by design.
            const int ip = (i + 1) & (TT - 1);
            const f16* xc1 = &xlds[(ip >> 3) & 1][(ip & 7) * 1024];
            f16x8 xn0 = *(const f16x8*)&xc1[(quad * 16 + lid) * 8];
            f16x8 xn1 = *(const f16x8*)&xc1[((4 + quad) * 16 + lid) * 8];
            f16x8 fr0 = *(const f16x8*)&h1b[PR][lid][quad * 8];
            f16x8 fr1 = *(const f16x8*)&h1b[PR][lid][32 + quad * 8];
            f16x8 fr2 = *(const f16x8*)&h1b[PR][lid][64 + quad * 8];
            f16x8 fr3 = *(const f16x8*)&h1b[PR][lid][96 + quad * 8];
            f32x4 acc[4];
#pragma unroll
            for (int g = 0; g < 4; ++g) {
                f32x4 a = mfma16(wt[g][0], fr0, czx[g]);   // C = b1 + W1*x[i]
                a = mfma16(wt[g][1], fr1, a);
                a = mfma16(wt[g][2], fr2, a);
                a = mfma16(wt[g][3], fr3, a);
                acc[g] = a;
            }
            // czx for step i+1 -- unconditional, fills the epilogue window
#pragma unroll
            for (int g = 0; g < 4; ++g)
                czx[g] = mfma16(wt[g][5], xn1, mfma16(wt[g][4], xn0, bsp[g]));
            f16x4 hp;
#pragma unroll
            for (int r = 0; r < 4; ++r) {
                const float ig = sigm2(acc[0][r]);
                const float fg = sigm2(acc[1][r]);
                const float gg = fmaxf(acc[2][r], 0.f);
                const float og = sigm2(acc[3][r]);
                const float cc = fg * cs[r] + ig * gg;
                cs[r] = cc;
                hp[r] = (f16)(og * fmaxf(cc, 0.f));
            }
            *(f16x4*)&h1b[PW][lid][16 * w + quad * 4] = hp;   // packed b64
        } else {
            if (i >= 1) {
                f16x8 fr0 = *(const f16x8*)&h1b[PR][lid][quad * 8];
                f16x8 fr1 = *(const f16x8*)&h1b[PR][lid][32 + quad * 8];
                f16x8 fr2 = *(const f16x8*)&h1b[PR][lid][64 + quad * 8];
                f16x8 fr3 = *(const f16x8*)&h1b[PR][lid][96 + quad * 8];
                f16x8 fr4 = *(const f16x8*)&h2b[QR][lid][quad * 8];
                f16x8 fr5 = *(const f16x8*)&h2b[QR][lid][32 + quad * 8];
                f32x4 acc[4];
#pragma unroll
                for (int g = 0; g < 4; ++g) {
                    f32x4 a = mfma16(wt[g][0], fr0, bsp[g]);
                    a = mfma16(wt[g][1], fr1, a);
                    a = mfma16(wt[g][2], fr2, a);
                    a = mfma16(wt[g][3], fr3, a);
                    a = mfma16(wt[g][4], fr4, a);
                    a = mfma16(wt[g][5], fr5, a);
                    acc[g] = a;
                }
                f16x4 hp;
#pragma unroll
                for (int r = 0; r < 4; ++r) {
                    const float ig = sigm2(acc[0][r]);
                    const float fg = sigm2(acc[1][r]);
                    const float gg = fmaxf(acc[2][r], 0.f);
                    const float og = sigm2(acc[3][r]);
                    const float cc = fg * cs[r] + ig * gg;
                    cs[r] = cc;
                    hp[r] = (f16)(og * fmaxf(cc, 0.f));
                }
                *(f16x4*)&h2b[QW][lid][16 * j + quad * 4] = hp;   // packed b64
            }
        }
    };

    // ---------------- main loop, unrolled x2: ONE barrier per step ----------------
    for (int ii = 0; ii < TT; ii += 2) {
        if ((ii & (XC - 1)) == 0 && ii + XC < TT) {
            const int nc = (ii >> 3) + 1;
            f16* dst = xlds[nc & 1];
            for (int s = tid; s < XC * 8 * 16; s += 768) {
                const int tl = s >> 7, fs = (s >> 4) & 7, row = s & 15;
                const f16* gp = xh + ((size_t)(b0 + row) * TT + (nc * XC + tl)) * FF + fs * 8;
                gl_lds16(gp, &dst[(s >> 6) * 512]);
            }
        }
        step(std::integral_constant<int, 0>{}, ii);
        __syncthreads();
        step(std::integral_constant<int, 1>{}, ii + 1);
        __syncthreads();
    }

    if (isL1) asm volatile("s_setprio 0");

    // final pipeline step i=TT (even): L2 consumes h1[TT-1], exports h2 f32
    if (!isL1) {
        f16x8 fr0 = *(const f16x8*)&h1b[1][lid][quad * 8];
        f16x8 fr1 = *(const f16x8*)&h1b[1][lid][32 + quad * 8];
        f16x8 fr2 = *(const f16x8*)&h1b[1][lid][64 + quad * 8];
        f16x8 fr3 = *(const f16x8*)&h1b[1][lid][96 + quad * 8];
        f16x8 fr4 = *(const f16x8*)&h2b[0][lid][quad * 8];
        f16x8 fr5 = *(const f16x8*)&h2b[0][lid][32 + quad * 8];
        f32x4 acc[4];
#pragma unroll
        for (int g = 0; g < 4; ++g) {
            f32x4 a = mfma16(wt[g][0], fr0, bsp[g]);
            a = mfma16(wt[g][1], fr1, a);
            a = mfma16(wt[g][2], fr2, a);
            a = mfma16(wt[g][3], fr3, a);
            a = mfma16(wt[g][4], fr4, a);
            a = mfma16(wt[g][5], fr5, a);
            acc[g] = a;
        }
        float4 ho;
#pragma unroll
        for (int r = 0; r < 4; ++r) {
            const float ig = sigm2(acc[0][r]);
            const float fg = sigm2(acc[1][r]);
            const float gg = fmaxf(acc[2][r], 0.f);
            const float og = sigm2(acc[3][r]);
            const float cc = fg * cs[r] + ig * gg;
            (&ho.x)[r] = og * fmaxf(cc, 0.f);
        }
        *(float4*)&h2f[lid][16 * j + quad * 4] = ho;   // [batch][unit]
    }
    __syncthreads();

    // ---------------- dense head ----------------
    for (int idx = tid; idx < 16 * D1; idx += 768) {
        const int bq = idx / D1, p = idx % D1;
        float d = bd1[p];
#pragma unroll
        for (int k = 0; k < H2; ++k) d += h2f[bq][k] * Wd1[k * D1 + p];
        dsh[bq][p] = d * Wd2[p];
    }
    __syncthreads();
    if (tid < 16) {
        float o = bd2[0];
#pragma unroll
        for (int p = 0; p < D1; ++p) o += dsh[tid][p];
        out[b0 + tid] = o;
    }
}

extern "C" void kernel_launch(void* const* d_in, const int* in_sizes, int n_in,
                              void* d_out, int out_size, void* d_ws, size_t ws_size,
                              hipStream_t stream) {
    (void)in_sizes; (void)n_in; (void)out_size; (void)ws_size;
    const float* x   = (const float*)d_in[0];
    const float* W1  = (const float*)d_in[1];
    const float* U1  = (const float*)d_in[2];
    const float* b1  = (const float*)d_in[3];
    const float* W2  = (const float*)d_in[4];
    const float* U2  = (const float*)d_in[5];
    const float* b2  = (const float*)d_in[6];
    const float* Wd1 = (const float*)d_in[7];
    const float* bd1 = (const float*)d_in[8];
    const float* Wd2 = (const float*)d_in[9];
    const float* bd2 = (const float*)d_in[10];
    float* out = (float*)d_out;
    f16*   xh  = (f16*)d_ws;    // 512*512*64 f16 = 32 MiB scratch

    const int nx = 512 * 512 * 64;
    cvt_x_kernel<<<dim3(nx / (256 * 4)), dim3(256), 0, stream>>>(x, xh);
    lstm_pipe12<<<dim3(32), dim3(768), 0, stream>>>(
        xh, W1, U1, b1, W2, U2, b2, Wd1, bd1, Wd2, bd2, out);
}

// Round 4
// 879.344 us; speedup vs baseline: 1.6867x; 1.3105x over previous
//
#include <hip/hip_runtime.h>
#include <type_traits>

typedef _Float16 f16;
typedef _Float16 f16x4 __attribute__((ext_vector_type(4)));
typedef _Float16 f16x8 __attribute__((ext_vector_type(8)));
typedef float    f32x4 __attribute__((ext_vector_type(4)));

constexpr int TT = 512;   // timesteps
constexpr int FF = 64;    // input features
constexpr int H1 = 128;   // layer-1 hidden (512 gate cols)
constexpr int H2 = 64;    // layer-2 hidden (256 gate cols)
constexpr int D1 = 25;    // dense-1 width
constexpr int S1 = 136;   // h1 LDS row stride (f16)
constexpr int S2 = 72;    // h2 LDS row stride
constexpr int XC = 8;     // x timesteps per staged LDS chunk
constexpr float L2E = 1.44269504088896f;

// z pre-scaled by log2(e) at weight-load time: sigmoid = rcp(1 + 2^-z).
__device__ __forceinline__ float sigm2(float z) {
    return __builtin_amdgcn_rcpf(1.f + __builtin_amdgcn_exp2f(-z));
}

__device__ __forceinline__ f32x4 mfma16(f16x8 a, f16x8 b, f32x4 c) {
    return __builtin_amdgcn_mfma_f32_16x16x32_f16(a, b, c, 0, 0, 0);
}

__device__ __forceinline__ void gl_lds16(const f16* g, f16* l) {
    __builtin_amdgcn_global_load_lds(
        (const __attribute__((address_space(1))) unsigned int*)g,
        (__attribute__((address_space(3))) unsigned int*)l, 16, 0, 0);
}

// pre-pass: x fp32 -> f16 so staging is a raw byte copy.
__global__ void cvt_x_kernel(const float* __restrict__ x, f16* __restrict__ xh) {
    const size_t i = ((size_t)blockIdx.x * blockDim.x + threadIdx.x) * 4;
    const float4 v = *(const float4*)(x + i);
    f16x4 h; h[0] = (f16)v.x; h[1] = (f16)v.y; h[2] = (f16)v.z; h[3] = (f16)v.w;
    *(f16x4*)(xh + i) = h;
}

// R18: pipe-overlap restructure. R14's counters (32-CU-scaled MfmaUtil 42%,
// VALUBusy 50%, ~additive) show the barrier-locked 12-wave structure
// serializes the MFMA burst and the VALU epilogue phases chip-wide. The 12
// column-groups (8 L1 + 4 L2, each = 16 gate cols x 4 gates) are remapped to
// 4 waves (256 thr, 1 wave/SIMD, __launch_bounds__(256,1) -> 512-reg budget):
// each wave owns 2 L1 groups (cg=2w, 2w+1) + 1 L2 group (cg=w). Within a
// wave, group B/C MFMAs are independent of group A's epilogue -> the
// scheduler overlaps matrix pipe and VALU that the old phase-locked waves
// left additive. Per-SIMD MFMA load unchanged (72/step). All per-tile math,
// LDS layouts, staging, parity identical to R14 (583 us). czx/chain-shaving
// abandoned (R16/R17: loop-carried f32x4 arrays demote to scratch).
__global__ __launch_bounds__(256, 1)
void lstm_q4(const f16* __restrict__ xh, const float* __restrict__ W1,
             const float* __restrict__ U1, const float* __restrict__ b1,
             const float* __restrict__ W2, const float* __restrict__ U2,
             const float* __restrict__ b2, const float* __restrict__ Wd1,
             const float* __restrict__ bd1,const float* __restrict__ Wd2,
             const float* __restrict__ bd2, float* __restrict__ out)
{
    const int tid  = threadIdx.x;
    const int w    = tid >> 6;      // wave 0..3 (one per SIMD)
    const int lane = tid & 63;
    const int quad = lane >> 4;
    const int lid  = lane & 15;
    const int b0   = blockIdx.x * 16;

    __shared__ __align__(16) f16 h1b[2][16][S1];
    __shared__ __align__(16) f16 h2b[2][16][S2];
    // x chunk layout: [tl(8)][fseg(8)][row(16)] of 8-f16 (16 B) segments.
    __shared__ __align__(16) f16 xlds[2][XC * 8 * 16 * 8];
    __shared__ float h2f[16][H2];
    __shared__ float dsh[16][D1];

    for (int i = tid; i < 2 * 16 * S1 / 2; i += 256) ((unsigned*)h1b)[i] = 0u;
    for (int i = tid; i < 2 * 16 * S2 / 2; i += 256) ((unsigned*)h2b)[i] = 0u;

    // stage x chunk 0 (timesteps 0..7) into xlds[0]
    for (int s = tid; s < XC * 8 * 16; s += 256) {
        const int tl = s >> 7, fs = (s >> 4) & 7, row = s & 15;
        const f16* gp = xh + ((size_t)(b0 + row) * TT + tl) * FF + fs * 8;
        gl_lds16(gp, &xlds[0][(s >> 6) * 512]);
    }

    // ---- weight fragments (A operand): lane holds col n=base+lid, rows
    // k = 32c + quad*8 + e. gates 0,1,3 (i,f,o) pre-scaled by log2e.
    // Groups A,B (L1, cg=2w,2w+1): chunks 0..3 = U1 (K=128), 4..5 = W1 (K=64)
    // Group  C (L2, cg=w):         chunks 0..3 = W2 (K=128), 4..5 = U2 (K=64)
    f16x8 wtA[4][6], wtB[4][6], wtC[4][6];
    f32x4 bspA[4], bspB[4], bspC[4];
    float csA[4] = {0.f, 0.f, 0.f, 0.f};
    float csB[4] = {0.f, 0.f, 0.f, 0.f};
    float csC[4] = {0.f, 0.f, 0.f, 0.f};

    {   // group A: cg = 2w
        const int cg = 2 * w;
#pragma unroll
        for (int g = 0; g < 4; ++g) {
            const float sc = (g == 2) ? 1.f : L2E;
            const int n = 128 * g + 16 * cg + lid;
#pragma unroll
            for (int rr = 0; rr < 4; ++rr)
                bspA[g][rr] = b1[128 * g + 16 * cg + quad * 4 + rr] * sc;
#pragma unroll
            for (int c = 0; c < 4; ++c) {
                f16x8 f;
#pragma unroll
                for (int e = 0; e < 8; ++e)
                    f[e] = (f16)(U1[(32 * c + quad * 8 + e) * 512 + n] * sc);
                wtA[g][c] = f;
            }
#pragma unroll
            for (int c = 0; c < 2; ++c) {
                f16x8 f;
#pragma unroll
                for (int e = 0; e < 8; ++e)
                    f[e] = (f16)(W1[(32 * c + quad * 8 + e) * 512 + n] * sc);
                wtA[g][4 + c] = f;
            }
        }
    }
    {   // group B: cg = 2w+1
        const int cg = 2 * w + 1;
#pragma unroll
        for (int g = 0; g < 4; ++g) {
            const float sc = (g == 2) ? 1.f : L2E;
            const int n = 128 * g + 16 * cg + lid;
#pragma unroll
            for (int rr = 0; rr < 4; ++rr)
                bspB[g][rr] = b1[128 * g + 16 * cg + quad * 4 + rr] * sc;
#pragma unroll
            for (int c = 0; c < 4; ++c) {
                f16x8 f;
#pragma unroll
                for (int e = 0; e < 8; ++e)
                    f[e] = (f16)(U1[(32 * c + quad * 8 + e) * 512 + n] * sc);
                wtB[g][c] = f;
            }
#pragma unroll
            for (int c = 0; c < 2; ++c) {
                f16x8 f;
#pragma unroll
                for (int e = 0; e < 8; ++e)
                    f[e] = (f16)(W1[(32 * c + quad * 8 + e) * 512 + n] * sc);
                wtB[g][4 + c] = f;
            }
        }
    }
    {   // group C: L2, cg = w
#pragma unroll
        for (int g = 0; g < 4; ++g) {
            const float sc = (g == 2) ? 1.f : L2E;
            const int n = 64 * g + 16 * w + lid;
#pragma unroll
            for (int rr = 0; rr < 4; ++rr)
                bspC[g][rr] = b2[64 * g + 16 * w + quad * 4 + rr] * sc;
#pragma unroll
            for (int c = 0; c < 4; ++c) {
                f16x8 f;
#pragma unroll
                for (int e = 0; e < 8; ++e)
                    f[e] = (f16)(W2[(32 * c + quad * 8 + e) * 256 + n] * sc);
                wtC[g][c] = f;
            }
#pragma unroll
            for (int c = 0; c < 2; ++c) {
                f16x8 f;
#pragma unroll
                for (int e = 0; e < 8; ++e)
                    f[e] = (f16)(U2[(32 * c + quad * 8 + e) * 256 + n] * sc);
                wtC[g][4 + c] = f;
            }
        }
    }
    __syncthreads();   // also drains chunk-0 staging vmcnt

    // one pipeline step; PAR = i&1 known at compile time => LDS immediates.
    // Program order A-MFMA, B-MFMA, epiA, C-MFMA, epiB, epiC lets the
    // scheduler overlap epilogue VALU with in-flight independent MFMAs.
    auto step = [&](auto parc, int i) {
        constexpr int PAR = decltype(parc)::value;
        constexpr int PR = PAR ^ 1;   // h1[i-1]
        constexpr int PW = PAR;       // h1[i]
        constexpr int QR = PAR;       // h2[i-2]
        constexpr int QW = PAR ^ 1;   // h2[i-1]
        const f16* xc = &xlds[(i >> 3) & 1][(i & 7) * 1024];
        // issue all LDS fragment reads up front (latency hiding)
        f16x8 xf0 = *(const f16x8*)&xc[(quad * 16 + lid) * 8];
        f16x8 xf1 = *(const f16x8*)&xc[((4 + quad) * 16 + lid) * 8];
        f16x8 fr0 = *(const f16x8*)&h1b[PR][lid][quad * 8];
        f16x8 fr1 = *(const f16x8*)&h1b[PR][lid][32 + quad * 8];
        f16x8 fr2 = *(const f16x8*)&h1b[PR][lid][64 + quad * 8];
        f16x8 fr3 = *(const f16x8*)&h1b[PR][lid][96 + quad * 8];
        f16x8 fr4 = *(const f16x8*)&h2b[QR][lid][quad * 8];
        f16x8 fr5 = *(const f16x8*)&h2b[QR][lid][32 + quad * 8];

        // ---- group A MFMAs (L1, cg=2w)
        f32x4 accA[4];
#pragma unroll
        for (int g = 0; g < 4; ++g) {
            f32x4 a = mfma16(wtA[g][0], fr0, bspA[g]);
            a = mfma16(wtA[g][1], fr1, a);
            a = mfma16(wtA[g][2], fr2, a);
            a = mfma16(wtA[g][3], fr3, a);
            a = mfma16(wtA[g][4], xf0, a);
            a = mfma16(wtA[g][5], xf1, a);
            accA[g] = a;
        }
        // ---- group B MFMAs (L1, cg=2w+1) -- independent of accA
        f32x4 accB[4];
#pragma unroll
        for (int g = 0; g < 4; ++g) {
            f32x4 a = mfma16(wtB[g][0], fr0, bspB[g]);
            a = mfma16(wtB[g][1], fr1, a);
            a = mfma16(wtB[g][2], fr2, a);
            a = mfma16(wtB[g][3], fr3, a);
            a = mfma16(wtB[g][4], xf0, a);
            a = mfma16(wtB[g][5], xf1, a);
            accB[g] = a;
        }
        // ---- epilogue A (VALU; overlaps with B/C MFMAs in flight)
        {
            f16x4 hp;
#pragma unroll
            for (int r = 0; r < 4; ++r) {
                const float ig = sigm2(accA[0][r]);
                const float fg = sigm2(accA[1][r]);
                const float gg = fmaxf(accA[2][r], 0.f);
                const float og = sigm2(accA[3][r]);
                const float cc = fg * csA[r] + ig * gg;
                csA[r] = cc;
                hp[r] = (f16)(og * fmaxf(cc, 0.f));
            }
            *(f16x4*)&h1b[PW][lid][16 * (2 * w) + quad * 4] = hp;
        }
        // ---- group C MFMAs (L2, step i-1), skip at i=0
        if (i >= 1) {
            f32x4 accC[4];
#pragma unroll
            for (int g = 0; g < 4; ++g) {
                f32x4 a = mfma16(wtC[g][0], fr0, bspC[g]);
                a = mfma16(wtC[g][1], fr1, a);
                a = mfma16(wtC[g][2], fr2, a);
                a = mfma16(wtC[g][3], fr3, a);
                a = mfma16(wtC[g][4], fr4, a);
                a = mfma16(wtC[g][5], fr5, a);
                accC[g] = a;
            }
            // ---- epilogue B
            {
                f16x4 hp;
#pragma unroll
                for (int r = 0; r < 4; ++r) {
                    const float ig = sigm2(accB[0][r]);
                    const float fg = sigm2(accB[1][r]);
                    const float gg = fmaxf(accB[2][r], 0.f);
                    const float og = sigm2(accB[3][r]);
                    const float cc = fg * csB[r] + ig * gg;
                    csB[r] = cc;
                    hp[r] = (f16)(og * fmaxf(cc, 0.f));
                }
                *(f16x4*)&h1b[PW][lid][16 * (2 * w + 1) + quad * 4] = hp;
            }
            // ---- epilogue C
            {
                f16x4 hp;
#pragma unroll
                for (int r = 0; r < 4; ++r) {
                    const float ig = sigm2(accC[0][r]);
                    const float fg = sigm2(accC[1][r]);
                    const float gg = fmaxf(accC[2][r], 0.f);
                    const float og = sigm2(accC[3][r]);
                    const float cc = fg * csC[r] + ig * gg;
                    csC[r] = cc;
                    hp[r] = (f16)(og * fmaxf(cc, 0.f));
                }
                *(f16x4*)&h2b[QW][lid][16 * w + quad * 4] = hp;
            }
        } else {
            // ---- epilogue B only (no L2 at i=0)
            f16x4 hp;
#pragma unroll
            for (int r = 0; r < 4; ++r) {
                const float ig = sigm2(accB[0][r]);
                const float fg = sigm2(accB[1][r]);
                const float gg = fmaxf(accB[2][r], 0.f);
                const float og = sigm2(accB[3][r]);
                const float cc = fg * csB[r] + ig * gg;
                csB[r] = cc;
                hp[r] = (f16)(og * fmaxf(cc, 0.f));
            }
            *(f16x4*)&h1b[PW][lid][16 * (2 * w + 1) + quad * 4] = hp;
        }
    };

    // ---------------- main loop, unrolled x2: ONE barrier per step ----------------
    for (int ii = 0; ii < TT; ii += 2) {
        if ((ii & (XC - 1)) == 0 && ii + XC < TT) {
            const int nc = (ii >> 3) + 1;
            f16* dst = xlds[nc & 1];
            for (int s = tid; s < XC * 8 * 16; s += 256) {
                const int tl = s >> 7, fs = (s >> 4) & 7, row = s & 15;
                const f16* gp = xh + ((size_t)(b0 + row) * TT + (nc * XC + tl)) * FF + fs * 8;
                gl_lds16(gp, &dst[(s >> 6) * 512]);
            }
        }
        step(std::integral_constant<int, 0>{}, ii);
        __syncthreads();
        step(std::integral_constant<int, 1>{}, ii + 1);
        __syncthreads();
    }

    // final pipeline step i=TT (even): L2 consumes h1[TT-1], exports h2 f32
    {
        f16x8 fr0 = *(const f16x8*)&h1b[1][lid][quad * 8];
        f16x8 fr1 = *(const f16x8*)&h1b[1][lid][32 + quad * 8];
        f16x8 fr2 = *(const f16x8*)&h1b[1][lid][64 + quad * 8];
        f16x8 fr3 = *(const f16x8*)&h1b[1][lid][96 + quad * 8];
        f16x8 fr4 = *(const f16x8*)&h2b[0][lid][quad * 8];
        f16x8 fr5 = *(const f16x8*)&h2b[0][lid][32 + quad * 8];
        f32x4 acc[4];
#pragma unroll
        for (int g = 0; g < 4; ++g) {
            f32x4 a = mfma16(wtC[g][0], fr0, bspC[g]);
            a = mfma16(wtC[g][1], fr1, a);
            a = mfma16(wtC[g][2], fr2, a);
            a = mfma16(wtC[g][3], fr3, a);
            a = mfma16(wtC[g][4], fr4, a);
            a = mfma16(wtC[g][5], fr5, a);
            acc[g] = a;
        }
        float4 ho;
#pragma unroll
        for (int r = 0; r < 4; ++r) {
            const float ig = sigm2(acc[0][r]);
            const float fg = sigm2(acc[1][r]);
            const float gg = fmaxf(acc[2][r], 0.f);
            const float og = sigm2(acc[3][r]);
            const float cc = fg * csC[r] + ig * gg;
            (&ho.x)[r] = og * fmaxf(cc, 0.f);
        }
        *(float4*)&h2f[lid][16 * w + quad * 4] = ho;   // [batch][unit]
    }
    __syncthreads();

    // ---------------- dense head ----------------
    for (int idx = tid; idx < 16 * D1; idx += 256) {
        const int bq = idx / D1, p = idx % D1;
        float d = bd1[p];
#pragma unroll
        for (int k = 0; k < H2; ++k) d += h2f[bq][k] * Wd1[k * D1 + p];
        dsh[bq][p] = d * Wd2[p];
    }
    __syncthreads();
    if (tid < 16) {
        float o = bd2[0];
#pragma unroll
        for (int p = 0; p < D1; ++p) o += dsh[tid][p];
        out[b0 + tid] = o;
    }
}

extern "C" void kernel_launch(void* const* d_in, const int* in_sizes, int n_in,
                              void* d_out, int out_size, void* d_ws, size_t ws_size,
                              hipStream_t stream) {
    (void)in_sizes; (void)n_in; (void)out_size; (void)ws_size;
    const float* x   = (const float*)d_in[0];
    const float* W1  = (const float*)d_in[1];
    const float* U1  = (const float*)d_in[2];
    const float* b1  = (const float*)d_in[3];
    const float* W2  = (const float*)d_in[4];
    const float* U2  = (const float*)d_in[5];
    const float* b2  = (const float*)d_in[6];
    const float* Wd1 = (const float*)d_in[7];
    const float* bd1 = (const float*)d_in[8];
    const float* Wd2 = (const float*)d_in[9];
    const float* bd2 = (const float*)d_in[10];
    float* out = (float*)d_out;
    f16*   xh  = (f16*)d_ws;    // 512*512*64 f16 = 32 MiB scratch

    const int nx = 512 * 512 * 64;
    cvt_x_kernel<<<dim3(nx / (256 * 4)), dim3(256), 0, stream>>>(x, xh);
    lstm_q4<<<dim3(32), dim3(256), 0, stream>>>(
        xh, W1, U1, b1, W2, U2, b2, Wd1, bd1, Wd2, bd2, out);
}

// Round 5
// 666.586 us; speedup vs baseline: 2.2250x; 1.3192x over previous
//
#include <hip/hip_runtime.h>
#include <type_traits>

typedef _Float16 f16;
typedef _Float16 f16x4 __attribute__((ext_vector_type(4)));
typedef _Float16 f16x8 __attribute__((ext_vector_type(8)));
typedef float    f32x4 __attribute__((ext_vector_type(4)));

constexpr int TT = 512;   // timesteps
constexpr int FF = 64;    // input features
constexpr int H1 = 128;   // layer-1 hidden (512 gate cols)
constexpr int H2 = 64;    // layer-2 hidden (256 gate cols)
constexpr int D1 = 25;    // dense-1 width
constexpr int S1 = 136;   // h1 LDS row stride (f16)
constexpr int S2 = 72;    // h2 LDS row stride
constexpr int XC = 8;     // x timesteps per staged LDS chunk
constexpr float L2E = 1.44269504088896f;

// z pre-scaled by log2(e) at weight-load time: sigmoid = rcp(1 + 2^-z).
__device__ __forceinline__ float sigm2(float z) {
    return __builtin_amdgcn_rcpf(1.f + __builtin_amdgcn_exp2f(-z));
}

__device__ __forceinline__ f32x4 mfma16(f16x8 a, f16x8 b, f32x4 c) {
    return __builtin_amdgcn_mfma_f32_16x16x32_f16(a, b, c, 0, 0, 0);
}

__device__ __forceinline__ void gl_lds16(const f16* g, f16* l) {
    __builtin_amdgcn_global_load_lds(
        (const __attribute__((address_space(1))) unsigned int*)g,
        (__attribute__((address_space(3))) unsigned int*)l, 16, 0, 0);
}

// sched_group_barrier masks (LLVM SchedGroupMask): VALU=0x2 MFMA=0x8
// DS_READ=0x100 DS_WRITE=0x200
#define SGB __builtin_amdgcn_sched_group_barrier

// pre-pass: x fp32 -> f16 so staging is a raw byte copy.
__global__ void cvt_x_kernel(const float* __restrict__ x, f16* __restrict__ xh) {
    const size_t i = ((size_t)blockIdx.x * blockDim.x + threadIdx.x) * 4;
    const float4 v = *(const float4*)(x + i);
    f16x4 h; h[0] = (f16)v.x; h[1] = (f16)v.y; h[2] = (f16)v.z; h[3] = (f16)v.w;
    *(f16x4*)(xh + i) = h;
}

// R19 = R14 (583 us kernel, best passing) + gate-staged epilogue interleave.
// R14 counters (32-CU-scaled): MFMA 42% + VALU 50% ~= additive -> the step is
// {MFMA phase}{VALU phase} serialized chip-wide because program order was
// {all 24 MFMAs}{full epilogue} and barrier-aligned waves phase-lock. R18
// proved 1 wave/SIMD is worse (VALU latency-bound: busy-cycles +48%), so we
// keep 12 waves / 3 per SIMD and interleave WITHIN the wave: sigma(gate g)
// is computed between gate g+1 and g+2's MFMA chains (gates independent;
// MFMA doesn't block its wave), pinned with sched_group_barrier recipes
// (MFMA x6 / VALU x12 alternation). FP math bit-identical to R14.
// Structure: 32 blocks x 768 threads. Waves 0-7: layer-1 step i. Waves 8-11:
// layer-2 step i-1. Ping-pong h1/h2 LDS => ONE barrier per step; x double-
// buffered via global_load_lds every 8 steps; s_setprio 1 on L1 waves.
__global__ __launch_bounds__(768, 3)
void lstm_pipe12(const f16* __restrict__ xh, const float* __restrict__ W1,
                 const float* __restrict__ U1, const float* __restrict__ b1,
                 const float* __restrict__ W2, const float* __restrict__ U2,
                 const float* __restrict__ b2, const float* __restrict__ Wd1,
                 const float* __restrict__ bd1,const float* __restrict__ Wd2,
                 const float* __restrict__ bd2, float* __restrict__ out)
{
    const int tid  = threadIdx.x;
    const int w    = tid >> 6;      // wave 0..11
    const int lane = tid & 63;
    const int quad = lane >> 4;
    const int lid  = lane & 15;
    const int b0   = blockIdx.x * 16;
    const bool isL1 = (w < 8);
    const int  j    = isL1 ? w : (w - 8);

    __shared__ __align__(16) f16 h1b[2][16][S1];
    __shared__ __align__(16) f16 h2b[2][16][S2];
    // x chunk layout: [tl(8)][fseg(8)][row(16)] of 8-f16 (16 B) segments.
    __shared__ __align__(16) f16 xlds[2][XC * 8 * 16 * 8];
    __shared__ float h2f[16][H2];
    __shared__ float dsh[16][D1];

    for (int i = tid; i < 2 * 16 * S1 / 2; i += 768) ((unsigned*)h1b)[i] = 0u;
    for (int i = tid; i < 2 * 16 * S2 / 2; i += 768) ((unsigned*)h2b)[i] = 0u;

    // stage x chunk 0 (timesteps 0..7) into xlds[0]
    for (int s = tid; s < XC * 8 * 16; s += 768) {
        const int tl = s >> 7, fs = (s >> 4) & 7, row = s & 15;
        const f16* gp = xh + ((size_t)(b0 + row) * TT + tl) * FF + fs * 8;
        gl_lds16(gp, &xlds[0][(s >> 6) * 512]);
    }

    // ---- weight fragments wt[g][c] (A operand): lane holds col n=base+lid,
    // rows k = 32c + quad*8 + e. gates 0,1,3 (i,f,o) pre-scaled by log2e.
    // L1 (w<8):  chunks 0..3 = U1 (h1, K=128), 4..5 = W1 (x, K=64)
    // L2 (w>=8): chunks 0..3 = W2 (h1, K=128), 4..5 = U2 (h2, K=64)
    f16x8 wt[4][6];
    f32x4 bsp[4];     // bias for this lane's 4 consecutive gate cols (C-init)
    float cs[4] = {0.f, 0.f, 0.f, 0.f};

    if (isL1) {
#pragma unroll
        for (int g = 0; g < 4; ++g) {
            const float sc = (g == 2) ? 1.f : L2E;
            const int n = 128 * g + 16 * w + lid;
#pragma unroll
            for (int rr = 0; rr < 4; ++rr)
                bsp[g][rr] = b1[128 * g + 16 * w + quad * 4 + rr] * sc;
#pragma unroll
            for (int c = 0; c < 4; ++c) {
                f16x8 f;
#pragma unroll
                for (int e = 0; e < 8; ++e)
                    f[e] = (f16)(U1[(32 * c + quad * 8 + e) * 512 + n] * sc);
                wt[g][c] = f;
            }
#pragma unroll
            for (int c = 0; c < 2; ++c) {
                f16x8 f;
#pragma unroll
                for (int e = 0; e < 8; ++e)
                    f[e] = (f16)(W1[(32 * c + quad * 8 + e) * 512 + n] * sc);
                wt[g][4 + c] = f;
            }
        }
    } else {
#pragma unroll
        for (int g = 0; g < 4; ++g) {
            const float sc = (g == 2) ? 1.f : L2E;
            const int n = 64 * g + 16 * j + lid;
#pragma unroll
            for (int rr = 0; rr < 4; ++rr)
                bsp[g][rr] = b2[64 * g + 16 * j + quad * 4 + rr] * sc;
#pragma unroll
            for (int c = 0; c < 4; ++c) {
                f16x8 f;
#pragma unroll
                for (int e = 0; e < 8; ++e)
                    f[e] = (f16)(W2[(32 * c + quad * 8 + e) * 256 + n] * sc);
                wt[g][c] = f;
            }
#pragma unroll
            for (int c = 0; c < 2; ++c) {
                f16x8 f;
#pragma unroll
                for (int e = 0; e < 8; ++e)
                    f[e] = (f16)(U2[(32 * c + quad * 8 + e) * 256 + n] * sc);
                wt[g][4 + c] = f;
            }
        }
    }
    __syncthreads();   // also drains chunk-0 staging vmcnt

    // bias issue arbitration toward the serial L1 recurrence
    if (isL1) asm volatile("s_setprio 1");

    // one pipeline step; PAR = i&1 known at compile time => LDS immediates.
    // D[m=quad*4+r][n=lid]: m = 4 consecutive gate cols, n = batch row.
    // Gate-staged epilogue: sigma(g) issued while gate g+1/g+2 MFMAs are in
    // the matrix pipe; SGB recipe pins {MFMA6,MFMA6,VALU12,MFMA6,VALU12,
    // MFMA6,...} so the scheduler can't re-cluster into phase-additive form.
    auto step = [&](auto parc, int i) {
        constexpr int PAR = decltype(parc)::value;
        constexpr int PR = PAR ^ 1;   // h1[i-1]
        constexpr int PW = PAR;       // h1[i]
        constexpr int QR = PAR;       // h2[i-2]
        constexpr int QW = PAR ^ 1;   // h2[i-1]
        if (isL1) {
            const f16* xc = &xlds[(i >> 3) & 1][(i & 7) * 1024];
            f16x8 fr0 = *(const f16x8*)&h1b[PR][lid][quad * 8];
            f16x8 fr1 = *(const f16x8*)&h1b[PR][lid][32 + quad * 8];
            f16x8 fr2 = *(const f16x8*)&h1b[PR][lid][64 + quad * 8];
            f16x8 fr3 = *(const f16x8*)&h1b[PR][lid][96 + quad * 8];
            f16x8 xf0 = *(const f16x8*)&xc[(quad * 16 + lid) * 8];
            f16x8 xf1 = *(const f16x8*)&xc[((4 + quad) * 16 + lid) * 8];
            // gate 0 chain
            f32x4 a0 = mfma16(wt[0][0], fr0, bsp[0]);
            a0 = mfma16(wt[0][1], fr1, a0);
            a0 = mfma16(wt[0][2], fr2, a0);
            a0 = mfma16(wt[0][3], fr3, a0);
            a0 = mfma16(wt[0][4], xf0, a0);
            a0 = mfma16(wt[0][5], xf1, a0);
            // gate 1 chain
            f32x4 a1 = mfma16(wt[1][0], fr0, bsp[1]);
            a1 = mfma16(wt[1][1], fr1, a1);
            a1 = mfma16(wt[1][2], fr2, a1);
            a1 = mfma16(wt[1][3], fr3, a1);
            a1 = mfma16(wt[1][4], xf0, a1);
            a1 = mfma16(wt[1][5], xf1, a1);
            // sigma(gate0) -- overlaps gate1/2 MFMAs
            float ig[4];
#pragma unroll
            for (int r = 0; r < 4; ++r) ig[r] = sigm2(a0[r]);
            // gate 2 chain
            f32x4 a2 = mfma16(wt[2][0], fr0, bsp[2]);
            a2 = mfma16(wt[2][1], fr1, a2);
            a2 = mfma16(wt[2][2], fr2, a2);
            a2 = mfma16(wt[2][3], fr3, a2);
            a2 = mfma16(wt[2][4], xf0, a2);
            a2 = mfma16(wt[2][5], xf1, a2);
            // sigma(gate1)
            float fg[4];
#pragma unroll
            for (int r = 0; r < 4; ++r) fg[r] = sigm2(a1[r]);
            // gate 3 chain
            f32x4 a3 = mfma16(wt[3][0], fr0, bsp[3]);
            a3 = mfma16(wt[3][1], fr1, a3);
            a3 = mfma16(wt[3][2], fr2, a3);
            a3 = mfma16(wt[3][3], fr3, a3);
            a3 = mfma16(wt[3][4], xf0, a3);
            a3 = mfma16(wt[3][5], xf1, a3);
            // relu(gate2), sigma(gate3), combine
            f16x4 hp;
#pragma unroll
            for (int r = 0; r < 4; ++r) {
                const float gg = fmaxf(a2[r], 0.f);
                const float og = sigm2(a3[r]);
                const float cc = fg[r] * cs[r] + ig[r] * gg;
                cs[r] = cc;
                hp[r] = (f16)(og * fmaxf(cc, 0.f));
            }
            *(f16x4*)&h1b[PW][lid][16 * w + quad * 4] = hp;   // packed b64
            // scheduling recipe: reads first, then MFMA/VALU interleave
            SGB(0x100, 6, 0);   // 6 ds_read (fr0-3, xf0-1)
            SGB(0x008, 6, 0);   // gate0 MFMA
            SGB(0x008, 6, 0);   // gate1 MFMA
            SGB(0x002, 12, 0);  // sigma(gate0)
            SGB(0x008, 6, 0);   // gate2 MFMA
            SGB(0x002, 12, 0);  // sigma(gate1)
            SGB(0x008, 6, 0);   // gate3 MFMA
            SGB(0x002, 20, 0);  // relu + sigma(gate3) + combine head
        } else {
            if (i >= 1) {
                f16x8 fr0 = *(const f16x8*)&h1b[PR][lid][quad * 8];
                f16x8 fr1 = *(const f16x8*)&h1b[PR][lid][32 + quad * 8];
                f16x8 fr2 = *(const f16x8*)&h1b[PR][lid][64 + quad * 8];
                f16x8 fr3 = *(const f16x8*)&h1b[PR][lid][96 + quad * 8];
                f16x8 fr4 = *(const f16x8*)&h2b[QR][lid][quad * 8];
                f16x8 fr5 = *(const f16x8*)&h2b[QR][lid][32 + quad * 8];
                // gate 0 chain
                f32x4 a0 = mfma16(wt[0][0], fr0, bsp[0]);
                a0 = mfma16(wt[0][1], fr1, a0);
                a0 = mfma16(wt[0][2], fr2, a0);
                a0 = mfma16(wt[0][3], fr3, a0);
                a0 = mfma16(wt[0][4], fr4, a0);
                a0 = mfma16(wt[0][5], fr5, a0);
                // gate 1 chain
                f32x4 a1 = mfma16(wt[1][0], fr0, bsp[1]);
                a1 = mfma16(wt[1][1], fr1, a1);
                a1 = mfma16(wt[1][2], fr2, a1);
                a1 = mfma16(wt[1][3], fr3, a1);
                a1 = mfma16(wt[1][4], fr4, a1);
                a1 = mfma16(wt[1][5], fr5, a1);
                // sigma(gate0)
                float ig[4];
#pragma unroll
                for (int r = 0; r < 4; ++r) ig[r] = sigm2(a0[r]);
                // gate 2 chain
                f32x4 a2 = mfma16(wt[2][0], fr0, bsp[2]);
                a2 = mfma16(wt[2][1], fr1, a2);
                a2 = mfma16(wt[2][2], fr2, a2);
                a2 = mfma16(wt[2][3], fr3, a2);
                a2 = mfma16(wt[2][4], fr4, a2);
                a2 = mfma16(wt[2][5], fr5, a2);
                // sigma(gate1)
                float fg[4];
#pragma unroll
                for (int r = 0; r < 4; ++r) fg[r] = sigm2(a1[r]);
                // gate 3 chain
                f32x4 a3 = mfma16(wt[3][0], fr0, bsp[3]);
                a3 = mfma16(wt[3][1], fr1, a3);
                a3 = mfma16(wt[3][2], fr2, a3);
                a3 = mfma16(wt[3][3], fr3, a3);
                a3 = mfma16(wt[3][4], fr4, a3);
                a3 = mfma16(wt[3][5], fr5, a3);
                // relu(gate2), sigma(gate3), combine
                f16x4 hp;
#pragma unroll
                for (int r = 0; r < 4; ++r) {
                    const float gg = fmaxf(a2[r], 0.f);
                    const float og = sigm2(a3[r]);
                    const float cc = fg[r] * cs[r] + ig[r] * gg;
                    cs[r] = cc;
                    hp[r] = (f16)(og * fmaxf(cc, 0.f));
                }
                *(f16x4*)&h2b[QW][lid][16 * j + quad * 4] = hp;   // packed b64
                SGB(0x100, 6, 0);   // 6 ds_read
                SGB(0x008, 6, 0);   // gate0 MFMA
                SGB(0x008, 6, 0);   // gate1 MFMA
                SGB(0x002, 12, 0);  // sigma(gate0)
                SGB(0x008, 6, 0);   // gate2 MFMA
                SGB(0x002, 12, 0);  // sigma(gate1)
                SGB(0x008, 6, 0);   // gate3 MFMA
                SGB(0x002, 20, 0);  // relu + sigma(gate3) + combine head
            }
        }
    };

    // ---------------- main loop, unrolled x2: ONE barrier per step ----------------
    for (int ii = 0; ii < TT; ii += 2) {
        if ((ii & (XC - 1)) == 0 && ii + XC < TT) {
            const int nc = (ii >> 3) + 1;
            f16* dst = xlds[nc & 1];
            for (int s = tid; s < XC * 8 * 16; s += 768) {
                const int tl = s >> 7, fs = (s >> 4) & 7, row = s & 15;
                const f16* gp = xh + ((size_t)(b0 + row) * TT + (nc * XC + tl)) * FF + fs * 8;
                gl_lds16(gp, &dst[(s >> 6) * 512]);
            }
        }
        step(std::integral_constant<int, 0>{}, ii);
        __syncthreads();
        step(std::integral_constant<int, 1>{}, ii + 1);
        __syncthreads();
    }

    if (isL1) asm volatile("s_setprio 0");

    // final pipeline step i=TT (even): L2 consumes h1[TT-1], exports h2 f32
    if (!isL1) {
        f16x8 fr0 = *(const f16x8*)&h1b[1][lid][quad * 8];
        f16x8 fr1 = *(const f16x8*)&h1b[1][lid][32 + quad * 8];
        f16x8 fr2 = *(const f16x8*)&h1b[1][lid][64 + quad * 8];
        f16x8 fr3 = *(const f16x8*)&h1b[1][lid][96 + quad * 8];
        f16x8 fr4 = *(const f16x8*)&h2b[0][lid][quad * 8];
        f16x8 fr5 = *(const f16x8*)&h2b[0][lid][32 + quad * 8];
        f32x4 acc[4];
#pragma unroll
        for (int g = 0; g < 4; ++g) {
            f32x4 a = mfma16(wt[g][0], fr0, bsp[g]);
            a = mfma16(wt[g][1], fr1, a);
            a = mfma16(wt[g][2], fr2, a);
            a = mfma16(wt[g][3], fr3, a);
            a = mfma16(wt[g][4], fr4, a);
            a = mfma16(wt[g][5], fr5, a);
            acc[g] = a;
        }
        float4 ho;
#pragma unroll
        for (int r = 0; r < 4; ++r) {
            const float ig = sigm2(acc[0][r]);
            const float fg = sigm2(acc[1][r]);
            const float gg = fmaxf(acc[2][r], 0.f);
            const float og = sigm2(acc[3][r]);
            const float cc = fg * cs[r] + ig * gg;
            (&ho.x)[r] = og * fmaxf(cc, 0.f);
        }
        *(float4*)&h2f[lid][16 * j + quad * 4] = ho;   // [batch][unit]
    }
    __syncthreads();

    // ---------------- dense head ----------------
    for (int idx = tid; idx < 16 * D1; idx += 768) {
        const int bq = idx / D1, p = idx % D1;
        float d = bd1[p];
#pragma unroll
        for (int k = 0; k < H2; ++k) d += h2f[bq][k] * Wd1[k * D1 + p];
        dsh[bq][p] = d * Wd2[p];
    }
    __syncthreads();
    if (tid < 16) {
        float o = bd2[0];
#pragma unroll
        for (int p = 0; p < D1; ++p) o += dsh[tid][p];
        out[b0 + tid] = o;
    }
}

extern "C" void kernel_launch(void* const* d_in, const int* in_sizes, int n_in,
                              void* d_out, int out_size, void* d_ws, size_t ws_size,
                              hipStream_t stream) {
    (void)in_sizes; (void)n_in; (void)out_size; (void)ws_size;
    const float* x   = (const float*)d_in[0];
    const float* W1  = (const float*)d_in[1];
    const float* U1  = (const float*)d_in[2];
    const float* b1  = (const float*)d_in[3];
    const float* W2  = (const float*)d_in[4];
    const float* U2  = (const float*)d_in[5];
    const float* b2  = (const float*)d_in[6];
    const float* Wd1 = (const float*)d_in[7];
    const float* bd1 = (const float*)d_in[8];
    const float* Wd2 = (const float*)d_in[9];
    const float* bd2 = (const float*)d_in[10];
    float* out = (float*)d_out;
    f16*   xh  = (f16*)d_ws;    // 512*512*64 f16 = 32 MiB scratch

    const int nx = 512 * 512 * 64;
    cvt_x_kernel<<<dim3(nx / (256 * 4)), dim3(256), 0, stream>>>(x, xh);
    lstm_pipe12<<<dim3(32), dim3(768), 0, stream>>>(
        xh, W1, U1, b1, W2, U2, b2, Wd1, bd1, Wd2, bd2, out);
}